// Round 4
// baseline (237.036 us; speedup 1.0000x reference)
//
#include <hip/hip_runtime.h>
#include <math.h>

// Problem constants
#define BB 2
#define HH 64
#define WW 64
#define DM 128
#define EE 256
#define NN 16
#define RR 8
#define HW (HH*WW)          // 4096

__device__ __forceinline__ float gelu_exact(float v) {
    return 0.5f * v * (1.f + erff(v * 0.70710678118654752440f));
}
__device__ __forceinline__ float softplus_f(float v) {
    return fmaxf(v, 0.f) + log1pf(__expf(-fabsf(v)));
}

// ---------------------------------------------------------------------------
// K1a: u = gelu(x@ipw^T + ipb) written transposed u_t[B,E,H,W].
// grid = (B*H rows) * 8 e-chunks of 32. block 256 thr.
// ---------------------------------------------------------------------------
__global__ __launch_bounds__(256) void k1a_u(
    const float* __restrict__ x,
    const float* __restrict__ ipw, const float* __restrict__ ipb,
    float* __restrict__ u_t)
{
    __shared__ float xs[64][129];

    const int blk = blockIdx.x;
    const int row = blk >> 3;            // b*64 + i
    const int ec  = blk & 7;
    const int b = row >> 6, i = row & 63;
    const int t = threadIdx.x;
    const int w = t >> 6, j = t & 63;

    const float* xrow = x + (size_t)row * (WW * DM);
    for (int idx = t; idx < WW * DM; idx += 256)
        xs[idx >> 7][idx & 127] = xrow[idx];
    __syncthreads();

    const int e0 = ec * 32 + w * 8;
    float acc[8];
    #pragma unroll
    for (int ee = 0; ee < 8; ++ee) acc[ee] = 0.f;

    for (int k = 0; k < DM; ++k) {
        const float xv = xs[j][k];
        #pragma unroll
        for (int ee = 0; ee < 8; ++ee)
            acc[ee] = fmaf(xv, ipw[(e0 + ee) * DM + k], acc[ee]);
    }
    #pragma unroll
    for (int ee = 0; ee < 8; ++ee) {
        const int e = e0 + ee;
        u_t[(((size_t)(b * EE + e) * HH + i) << 6) + j] = gelu_exact(acc[ee] + ipb[e]);
    }
}

// ---------------------------------------------------------------------------
// K1b: dbc = u@xpw^T + xpb; deltaT/L = softplus(d@dtw^T + b); Bm/Cm split.
// Block per (b,i,j-quarter): 512 blocks, 256 thr.
// ---------------------------------------------------------------------------
__global__ __launch_bounds__(256) void k1b_proj(
    const float* __restrict__ u_t,
    const float* __restrict__ xpw, const float* __restrict__ xpb,
    const float* __restrict__ dtTw, const float* __restrict__ dtTb,
    const float* __restrict__ dtLw, const float* __restrict__ dtLb,
    float* __restrict__ dT_t, float* __restrict__ dL_t,
    float* __restrict__ Bm_t, float* __restrict__ Cm_t)
{
    __shared__ float usT[16][260];     // [jj][e]
    __shared__ float xpwL[48][260];    // [c][e]
    __shared__ float dbcs[48][17];

    const int blk = blockIdx.x;        // (b*64+i)*4 + jq
    const int jq = blk & 3;
    const int row = blk >> 2;
    const int b = row >> 6, i = row & 63;
    const int j0 = jq * 16;
    const int t = threadIdx.x;

    for (int idx = t; idx < 48 * 64; idx += 256) {
        const int c = idx >> 6, e4 = idx & 63;
        const float4 v = ((const float4*)xpw)[(size_t)c * 64 + e4];
        *(float4*)&xpwL[c][4 * e4] = v;
    }
    {
        const int jj = t & 15, eg = t >> 4;
        #pragma unroll
        for (int r = 0; r < 16; ++r) {
            const int e = eg * 16 + r;
            usT[jj][e] = u_t[(((size_t)(b * EE + e) * HH + i) << 6) + j0 + jj];
        }
    }
    __syncthreads();

    {
        const int jj = t & 15, cg = t >> 4;
        float a0 = 0.f, a1 = 0.f, a2 = 0.f;
        for (int e4 = 0; e4 < 64; ++e4) {
            const float4 uv = *(const float4*)&usT[jj][4 * e4];
            const float4 w0 = *(const float4*)&xpwL[3 * cg + 0][4 * e4];
            const float4 w1 = *(const float4*)&xpwL[3 * cg + 1][4 * e4];
            const float4 w2 = *(const float4*)&xpwL[3 * cg + 2][4 * e4];
            a0 = fmaf(uv.x, w0.x, a0); a0 = fmaf(uv.y, w0.y, a0);
            a0 = fmaf(uv.z, w0.z, a0); a0 = fmaf(uv.w, w0.w, a0);
            a1 = fmaf(uv.x, w1.x, a1); a1 = fmaf(uv.y, w1.y, a1);
            a1 = fmaf(uv.z, w1.z, a1); a1 = fmaf(uv.w, w1.w, a1);
            a2 = fmaf(uv.x, w2.x, a2); a2 = fmaf(uv.y, w2.y, a2);
            a2 = fmaf(uv.z, w2.z, a2); a2 = fmaf(uv.w, w2.w, a2);
        }
        dbcs[3 * cg + 0][jj] = a0 + xpb[3 * cg + 0];
        dbcs[3 * cg + 1][jj] = a1 + xpb[3 * cg + 1];
        dbcs[3 * cg + 2][jj] = a2 + xpb[3 * cg + 2];
    }
    __syncthreads();

    {
        const int n = t >> 4, jj = t & 15;
        Bm_t[(((size_t)(b * NN + n) * HH + i) << 6) + j0 + jj] = dbcs[2 * RR + n][jj];
        Cm_t[(((size_t)(b * NN + n) * HH + i) << 6) + j0 + jj] = dbcs[2 * RR + NN + n][jj];
    }

    {
        const int jj = t & 15, eg = t >> 4;
        float dtv[8], dlv[8];
        #pragma unroll
        for (int r = 0; r < 8; ++r) { dtv[r] = dbcs[r][jj]; dlv[r] = dbcs[RR + r][jj]; }
        #pragma unroll 4
        for (int ee = 0; ee < 16; ++ee) {
            const int e = eg * 16 + ee;
            float sT = dtTb[e], sL = dtLb[e];
            #pragma unroll
            for (int r = 0; r < 8; ++r) {
                sT = fmaf(dtv[r], dtTw[e * RR + r], sT);
                sL = fmaf(dlv[r], dtLw[e * RR + r], sL);
            }
            dT_t[(((size_t)(b * EE + e) * HH + i) << 6) + j0 + jj] = softplus_f(sT);
            dL_t[(((size_t)(b * EE + e) * HH + i) << 6) + j0 + jj] = softplus_f(sL);
        }
    }
}

// ---------------------------------------------------------------------------
// K2: wavefront scan, one WAVE per (b,e). 64 threads, zero LDS, zero barriers.
// Lane = (c, jj): c = lane>>4, jj = lane&15. Lane owns 4 channels n = 4m+c
// and 4 cols 4jj..4jj+3. Per row: per-channel local scan of 4 + 4-step
// masked shfl_up over 16 lane-aggregates + prefix shift (4 independent
// chains), channel reduce via shfl_xor(16)+shfl_xor(32). c==0 lanes store
// float4. Next-row loads prefetched (h-independent).
// ---------------------------------------------------------------------------
__global__ __launch_bounds__(64) void k2_scan(
    const float* __restrict__ u_t, const float* __restrict__ dT_t,
    const float* __restrict__ dL_t, const float* __restrict__ Bm_t,
    const float* __restrict__ Cm_t, const float* __restrict__ ATl,
    const float* __restrict__ ALl, const float* __restrict__ Dp,
    float* __restrict__ ys_t)
{
    const int be = blockIdx.x;           // b*256 + e
    const int b = be >> 8, e = be & 255;
    const int lane = threadIdx.x;
    const int c = lane >> 4, jj = lane & 15;

    const float LOG2E = 1.44269504088896340736f;
    float AT2[4], AL2[4];
    #pragma unroll
    for (int m = 0; m < 4; ++m) {
        const int n = 4 * m + c;
        AT2[m] = -__expf(ATl[e * NN + n]) * LOG2E;
        AL2[m] = -__expf(ALl[e * NN + n]) * LOG2E;
    }
    const float De = Dp[e];

    const float* dTp = dT_t + ((size_t)be << 12) + 4 * jj;
    const float* dLp = dL_t + ((size_t)be << 12) + 4 * jj;
    const float* up  = u_t  + ((size_t)be << 12) + 4 * jj;
    const float* bmp[4];
    const float* cmp[4];
    #pragma unroll
    for (int m = 0; m < 4; ++m) {
        const int n = 4 * m + c;
        bmp[m] = Bm_t + ((size_t)(b * NN + n) << 12) + 4 * jj;
        cmp[m] = Cm_t + ((size_t)(b * NN + n) << 12) + 4 * jj;
    }
    float* ysp = ys_t + ((size_t)be << 12) + 4 * jj;

    float h[4][4];
    #pragma unroll
    for (int m = 0; m < 4; ++m)
        #pragma unroll
        for (int k = 0; k < 4; ++k) h[m][k] = 0.f;

    // prefetch row 0
    float4 dT4 = *(const float4*)dTp;
    float4 dL4 = *(const float4*)dLp;
    float4 u4  = *(const float4*)up;
    float4 bm4[4], cm4[4];
    #pragma unroll
    for (int m = 0; m < 4; ++m) { bm4[m] = *(const float4*)bmp[m]; cm4[m] = *(const float4*)cmp[m]; }

    for (int i = 0; i < HH; ++i) {
        // prefetch row i+1 (clamped; independent of h chain)
        const int ip = (i < HH - 1) ? (i + 1) : i;
        const float4 dT4n = *(const float4*)(dTp + (ip << 6));
        const float4 dL4n = *(const float4*)(dLp + (ip << 6));
        const float4 u4n  = *(const float4*)(up  + (ip << 6));
        float4 bm4n[4], cm4n[4];
        #pragma unroll
        for (int m = 0; m < 4; ++m) {
            bm4n[m] = *(const float4*)(bmp[m] + (ip << 6));
            cm4n[m] = *(const float4*)(cmp[m] + (ip << 6));
        }

        const float dTv[4] = {dT4.x, dT4.y, dT4.z, dT4.w};
        const float dLv[4] = {dL4.x, dL4.y, dL4.z, dL4.w};
        const float uv[4]  = {u4.x,  u4.y,  u4.z,  u4.w};
        float pre[4];
        #pragma unroll
        for (int k = 0; k < 4; ++k) pre[k] = (dTv[k] + dLv[k]) * uv[k];

        float ssum[4] = {0.f, 0.f, 0.f, 0.f};

        #pragma unroll
        for (int m = 0; m < 4; ++m) {
            const float bmv[4] = {bm4[m].x, bm4[m].y, bm4[m].z, bm4[m].w};
            const float cmv[4] = {cm4[m].x, cm4[m].y, cm4[m].z, cm4[m].w};
            float cumA[4], cumB[4];
            {
                const float aT = exp2f(dTv[0] * AT2[m]);
                const float aL = exp2f(dLv[0] * AL2[m]);
                cumB[0] = fmaf(aT, h[m][0], pre[0] * bmv[0]);
                cumA[0] = aL;
            }
            #pragma unroll
            for (int k = 1; k < 4; ++k) {
                const float aT = exp2f(dTv[k] * AT2[m]);
                const float aL = exp2f(dLv[k] * AL2[m]);
                const float bk = fmaf(aT, h[m][k], pre[k] * bmv[k]);
                cumB[k] = fmaf(aL, cumB[k - 1], bk);
                cumA[k] = aL * cumA[k - 1];
            }
            // 16-lane segmented Hillis-Steele on aggregates
            float Ag = cumA[3], Bg = cumB[3];
            #pragma unroll
            for (int s = 1; s < 8; s <<= 1) {
                const float uA = __shfl_up(Ag, (unsigned)s, 64);
                const float uB = __shfl_up(Bg, (unsigned)s, 64);
                if (jj >= s) { Bg = fmaf(Ag, uB, Bg); Ag *= uA; }
            }
            {   // last step: Ag no longer needed afterward
                const float uB = __shfl_up(Bg, 8u, 64);
                if (jj >= 8) Bg = fmaf(Ag, uB, Bg);
            }
            float pB = __shfl_up(Bg, 1u, 64);
            if (jj == 0) pB = 0.f;

            #pragma unroll
            for (int k = 0; k < 4; ++k) {
                const float hh = fmaf(cumA[k], pB, cumB[k]);
                h[m][k] = hh;
                ssum[k] = fmaf(hh, cmv[k], ssum[k]);
            }
        }

        // cross-c channel reduce (in-register)
        #pragma unroll
        for (int k = 0; k < 4; ++k) {
            ssum[k] += __shfl_xor(ssum[k], 16, 64);
            ssum[k] += __shfl_xor(ssum[k], 32, 64);
        }

        if (c == 0) {
            float4 o;
            o.x = gelu_exact(fmaf(uv[0], De, ssum[0]));
            o.y = gelu_exact(fmaf(uv[1], De, ssum[1]));
            o.z = gelu_exact(fmaf(uv[2], De, ssum[2]));
            o.w = gelu_exact(fmaf(uv[3], De, ssum[3]));
            *(float4*)(ysp + (i << 6)) = o;
        }

        dT4 = dT4n; dL4 = dL4n; u4 = u4n;
        #pragma unroll
        for (int m = 0; m < 4; ++m) { bm4[m] = bm4n[m]; cm4[m] = cm4n[m]; }
    }
}

// ---------------------------------------------------------------------------
// K3: out projection. grid = (B*H rows) * 4 d-chunks of 32.
// ---------------------------------------------------------------------------
__global__ __launch_bounds__(256) void k3_outproj(
    const float* __restrict__ ys_t,
    const float* __restrict__ ow, const float* __restrict__ ob,
    float* __restrict__ out)
{
    __shared__ float ysL[64][65];

    const int blk = blockIdx.x;
    const int row = blk >> 2;
    const int dc  = blk & 3;
    const int b = row >> 6, i = row & 63;
    const int t = threadIdx.x;
    const int w = t >> 6, j = t & 63;
    const int d0 = dc * 32 + w * 8;

    float acc[8];
    #pragma unroll
    for (int dd = 0; dd < 8; ++dd) acc[dd] = 0.f;

    for (int ch = 0; ch < 4; ++ch) {
        __syncthreads();
        for (int idx = t; idx < 64 * 64; idx += 256) {
            const int ee = idx >> 6, jj = idx & 63;
            ysL[ee][jj] = ys_t[(((size_t)(b * EE + ch * 64 + ee) * HH + i) << 6) + jj];
        }
        __syncthreads();
        for (int e64 = 0; e64 < 64; ++e64) {
            const float yv = ysL[e64][j];
            const int e = ch * 64 + e64;
            #pragma unroll
            for (int dd = 0; dd < 8; ++dd)
                acc[dd] = fmaf(ow[(d0 + dd) * EE + e], yv, acc[dd]);
        }
    }

    float* orow = out + (size_t)row * (WW * DM) + (size_t)j * DM + d0;
    #pragma unroll
    for (int dd = 0; dd < 8; ++dd) orow[dd] = acc[dd] + ob[d0 + dd];
}

extern "C" void kernel_launch(void* const* d_in, const int* in_sizes, int n_in,
                              void* d_out, int out_size, void* d_ws, size_t ws_size,
                              hipStream_t stream) {
    const float* x    = (const float*)d_in[0];
    const float* ipw  = (const float*)d_in[1];
    const float* ipb  = (const float*)d_in[2];
    const float* xpw  = (const float*)d_in[3];
    const float* xpb  = (const float*)d_in[4];
    const float* dtTw = (const float*)d_in[5];
    const float* dtTb = (const float*)d_in[6];
    const float* dtLw = (const float*)d_in[7];
    const float* dtLb = (const float*)d_in[8];
    const float* ATl  = (const float*)d_in[9];
    const float* ALl  = (const float*)d_in[10];
    const float* Dp   = (const float*)d_in[11];
    const float* ow   = (const float*)d_in[12];
    const float* ob   = (const float*)d_in[13];
    float* out = (float*)d_out;

    float* ws   = (float*)d_ws;
    float* u_t  = ws;
    float* dT_t = u_t  + (size_t)BB * EE * HW;
    float* dL_t = dT_t + (size_t)BB * EE * HW;
    float* ys_t = dL_t + (size_t)BB * EE * HW;
    float* Bm_t = ys_t + (size_t)BB * EE * HW;
    float* Cm_t = Bm_t + (size_t)BB * NN * HW;

    k1a_u<<<BB * HH * 8, 256, 0, stream>>>(x, ipw, ipb, u_t);
    k1b_proj<<<BB * HH * 4, 256, 0, stream>>>(u_t, xpw, xpb, dtTw, dtTb, dtLw, dtLb,
                                              dT_t, dL_t, Bm_t, Cm_t);
    k2_scan<<<BB * EE, 64, 0, stream>>>(u_t, dT_t, dL_t, Bm_t, Cm_t,
                                        ATl, ALl, Dp, ys_t);
    k3_outproj<<<BB * HH * 4, 256, 0, stream>>>(ys_t, ow, ob, out);
}

// Round 5
// 211.254 us; speedup vs baseline: 1.1220x; 1.1220x over previous
//
#include <hip/hip_runtime.h>
#include <math.h>

// Problem constants
#define BB 2
#define HH 64
#define WW 64
#define DM 128
#define EE 256
#define NN 16
#define RR 8
#define HW (HH*WW)          // 4096

__device__ __forceinline__ float gelu_exact(float v) {
    return 0.5f * v * (1.f + erff(v * 0.70710678118654752440f));
}
__device__ __forceinline__ float softplus_f(float v) {
    return fmaxf(v, 0.f) + log1pf(__expf(-fabsf(v)));
}

// ---------------------------------------------------------------------------
// K1a: u = gelu(x@ipw^T + ipb) written transposed u_t[B,E,H,W].
// grid = (B*H rows) * 8 e-chunks of 32. block 256 thr. (unchanged)
// ---------------------------------------------------------------------------
__global__ __launch_bounds__(256) void k1a_u(
    const float* __restrict__ x,
    const float* __restrict__ ipw, const float* __restrict__ ipb,
    float* __restrict__ u_t)
{
    __shared__ float xs[64][129];

    const int blk = blockIdx.x;
    const int row = blk >> 3;            // b*64 + i
    const int ec  = blk & 7;
    const int b = row >> 6, i = row & 63;
    const int t = threadIdx.x;
    const int w = t >> 6, j = t & 63;

    const float* xrow = x + (size_t)row * (WW * DM);
    for (int idx = t; idx < WW * DM; idx += 256)
        xs[idx >> 7][idx & 127] = xrow[idx];
    __syncthreads();

    const int e0 = ec * 32 + w * 8;
    float acc[8];
    #pragma unroll
    for (int ee = 0; ee < 8; ++ee) acc[ee] = 0.f;

    for (int k = 0; k < DM; ++k) {
        const float xv = xs[j][k];
        #pragma unroll
        for (int ee = 0; ee < 8; ++ee)
            acc[ee] = fmaf(xv, ipw[(e0 + ee) * DM + k], acc[ee]);
    }
    #pragma unroll
    for (int ee = 0; ee < 8; ++ee) {
        const int e = e0 + ee;
        u_t[(((size_t)(b * EE + e) * HH + i) << 6) + j] = gelu_exact(acc[ee] + ipb[e]);
    }
}

// ---------------------------------------------------------------------------
// K1b (rewritten): block per (b,i), 512 thr = 8 waves. Wave w owns channels
// c = 6w..6w+5 (wave-uniform xpw reads -> s_load, NO weight staging).
// u read directly from u_t, coalesced along j (lane = column). dbc in LDS,
// then Bm/Cm split + softplus deltas, all coalesced stores.
// ---------------------------------------------------------------------------
__global__ __launch_bounds__(512) void k1b_proj(
    const float* __restrict__ u_t,
    const float* __restrict__ xpw, const float* __restrict__ xpb,
    const float* __restrict__ dtTw, const float* __restrict__ dtTb,
    const float* __restrict__ dtLw, const float* __restrict__ dtLb,
    float* __restrict__ dT_t, float* __restrict__ dL_t,
    float* __restrict__ Bm_t, float* __restrict__ Cm_t)
{
    __shared__ float dbcs[48][68];

    const int row = blockIdx.x;          // b*64 + i
    const int b = row >> 6, i = row & 63;
    const int t = threadIdx.x;
    const int w = t >> 6;                // 0..7
    const int j = t & 63;

    const float* ubase = u_t + (((size_t)(b * EE) * HH + i) << 6) + j;
    const int c0 = 6 * w;

    float acc[6];
    #pragma unroll
    for (int cc = 0; cc < 6; ++cc) acc[cc] = 0.f;

    for (int e = 0; e < EE; e += 4) {
        const float uv0 = ubase[(size_t)(e + 0) << 12];
        const float uv1 = ubase[(size_t)(e + 1) << 12];
        const float uv2 = ubase[(size_t)(e + 2) << 12];
        const float uv3 = ubase[(size_t)(e + 3) << 12];
        #pragma unroll
        for (int cc = 0; cc < 6; ++cc) {
            const float* wrow = xpw + (size_t)(c0 + cc) * EE + e;
            float a = acc[cc];
            a = fmaf(uv0, wrow[0], a);
            a = fmaf(uv1, wrow[1], a);
            a = fmaf(uv2, wrow[2], a);
            a = fmaf(uv3, wrow[3], a);
            acc[cc] = a;
        }
    }
    #pragma unroll
    for (int cc = 0; cc < 6; ++cc)
        dbcs[c0 + cc][j] = acc[cc] + xpb[c0 + cc];
    __syncthreads();

    // Bm / Cm: wave w -> n = 2w, 2w+1 (dbc rows 16+n and 32+n)
    #pragma unroll
    for (int q = 0; q < 2; ++q) {
        const int n = 2 * w + q;
        Bm_t[(((size_t)(b * NN + n) * HH + i) << 6) + j] = dbcs[16 + n][j];
        Cm_t[(((size_t)(b * NN + n) * HH + i) << 6) + j] = dbcs[32 + n][j];
    }

    // deltas: wave w -> e in [32w, 32w+32)
    float dtv[8], dlv[8];
    #pragma unroll
    for (int r = 0; r < 8; ++r) { dtv[r] = dbcs[r][j]; dlv[r] = dbcs[8 + r][j]; }
    #pragma unroll 4
    for (int ee = 0; ee < 32; ++ee) {
        const int e = 32 * w + ee;
        float sT = dtTb[e], sL = dtLb[e];
        #pragma unroll
        for (int r = 0; r < 8; ++r) {
            sT = fmaf(dtv[r], dtTw[e * RR + r], sT);
            sL = fmaf(dlv[r], dtLw[e * RR + r], sL);
        }
        dT_t[(((size_t)(b * EE + e) * HH + i) << 6) + j] = softplus_f(sT);
        dL_t[(((size_t)(b * EE + e) * HH + i) << 6) + j] = softplus_f(sL);
    }
}

// ---------------------------------------------------------------------------
// K2: wavefront scan. Block per (b,e): 256 thr = 4 waves (R3 shape).
// Lane (c = lane>>4, jj = lane&15): channel n = 4w+c, cols 4jj..4jj+3.
// Per row: local scan of 4 + 4-step masked shfl_up + prefix shift; every lane
// writes its channel contribution float4 to padded part[2][16][68] (conflict-
// free per quarter-wave); ONE barrier/row (double-buffered); finalize
// distributed: wave w owns cols 16w..16w+15 (4 b32 LDS reads + 2 shfl_xor +
// gelu + store on its c==0 lanes). gelu is off the h critical path.
// ---------------------------------------------------------------------------
__global__ __launch_bounds__(256) void k2_scan(
    const float* __restrict__ u_t, const float* __restrict__ dT_t,
    const float* __restrict__ dL_t, const float* __restrict__ Bm_t,
    const float* __restrict__ Cm_t, const float* __restrict__ ATl,
    const float* __restrict__ ALl, const float* __restrict__ Dp,
    float* __restrict__ ys_t)
{
    __shared__ float part[2][NN][68];

    const int be = blockIdx.x;           // b*256 + e
    const int b = be >> 8, e = be & 255;
    const int t = threadIdx.x;
    const int w = t >> 6, lane = t & 63;
    const int c = lane >> 4, jj = lane & 15;
    const int n = w * 4 + c;

    const float LOG2E = 1.44269504088896340736f;
    const float AT2 = -__expf(ATl[e * NN + n]) * LOG2E;
    const float AL2 = -__expf(ALl[e * NN + n]) * LOG2E;
    const float De = Dp[e];

    const float* dTp = dT_t + ((size_t)be << 12) + 4 * jj;
    const float* dLp = dL_t + ((size_t)be << 12) + 4 * jj;
    const float* up  = u_t  + ((size_t)be << 12) + 4 * jj;
    const float* bmp = Bm_t + ((size_t)(b * NN + n) << 12) + 4 * jj;
    const float* cmp = Cm_t + ((size_t)(b * NN + n) << 12) + 4 * jj;

    // finalize slice: wave w owns cols 16w + jj
    const int fcol = 16 * w + jj;
    const float* ufin = u_t + ((size_t)be << 12) + fcol;
    float* ysfin = ys_t + ((size_t)be << 12) + fcol;

    float h[4] = {0.f, 0.f, 0.f, 0.f};

    // prefetch row 0
    float4 dT4 = *(const float4*)dTp;
    float4 dL4 = *(const float4*)dLp;
    float4 u4  = *(const float4*)up;
    float4 bm4 = *(const float4*)bmp;
    float4 cm4 = *(const float4*)cmp;
    float  uf  = *ufin;

    for (int i = 0; i < HH; ++i) {
        const int ip = (i < HH - 1) ? (i + 1) : i;
        const float4 dT4n = *(const float4*)(dTp + (ip << 6));
        const float4 dL4n = *(const float4*)(dLp + (ip << 6));
        const float4 u4n  = *(const float4*)(up  + (ip << 6));
        const float4 bm4n = *(const float4*)(bmp + (ip << 6));
        const float4 cm4n = *(const float4*)(cmp + (ip << 6));
        const float  ufn  = ufin[ip << 6];

        const float dTv[4] = {dT4.x, dT4.y, dT4.z, dT4.w};
        const float dLv[4] = {dL4.x, dL4.y, dL4.z, dL4.w};
        const float uv[4]  = {u4.x,  u4.y,  u4.z,  u4.w};
        const float bmv[4] = {bm4.x, bm4.y, bm4.z, bm4.w};
        const float cmv[4] = {cm4.x, cm4.y, cm4.z, cm4.w};

        // local inclusive scan over 4 cols (one channel per lane)
        float cumA[4], cumB[4];
        {
            const float aT = exp2f(dTv[0] * AT2);
            const float aL = exp2f(dLv[0] * AL2);
            cumB[0] = fmaf(aT, h[0], (dTv[0] + dLv[0]) * bmv[0] * uv[0]);
            cumA[0] = aL;
        }
        #pragma unroll
        for (int k = 1; k < 4; ++k) {
            const float aT = exp2f(dTv[k] * AT2);
            const float aL = exp2f(dLv[k] * AL2);
            const float bk = fmaf(aT, h[k], (dTv[k] + dLv[k]) * bmv[k] * uv[k]);
            cumB[k] = fmaf(aL, cumB[k - 1], bk);
            cumA[k] = aL * cumA[k - 1];
        }
        // 16-lane segmented Hillis-Steele on aggregates
        float Ag = cumA[3], Bg = cumB[3];
        #pragma unroll
        for (int s = 1; s < 8; s <<= 1) {
            const float uA = __shfl_up(Ag, (unsigned)s, 64);
            const float uB = __shfl_up(Bg, (unsigned)s, 64);
            if (jj >= s) { Bg = fmaf(Ag, uB, Bg); Ag *= uA; }
        }
        {
            const float uB = __shfl_up(Bg, 8u, 64);
            if (jj >= 8) Bg = fmaf(Ag, uB, Bg);
        }
        float pB = __shfl_up(Bg, 1u, 64);
        if (jj == 0) pB = 0.f;

        float g[4];
        #pragma unroll
        for (int k = 0; k < 4; ++k) {
            const float hh = fmaf(cumA[k], pB, cumB[k]);
            h[k] = hh;
            g[k] = hh * cmv[k];
        }

        const int buf = i & 1;
        *(float4*)&part[buf][n][4 * jj] = make_float4(g[0], g[1], g[2], g[3]);
        __syncthreads();

        // distributed finalize: wave w sums all 16 channel rows at col fcol
        float p0 = part[buf][c +  0][fcol];
        float p1 = part[buf][c +  4][fcol];
        float p2 = part[buf][c +  8][fcol];
        float p3 = part[buf][c + 12][fcol];
        float ps = (p0 + p1) + (p2 + p3);
        ps += __shfl_xor(ps, 16, 64);
        ps += __shfl_xor(ps, 32, 64);
        if (c == 0) {
            ysfin[i << 6] = gelu_exact(fmaf(uf, De, ps));
        }

        dT4 = dT4n; dL4 = dL4n; u4 = u4n; bm4 = bm4n; cm4 = cm4n; uf = ufn;
    }
}

// ---------------------------------------------------------------------------
// K3: out projection. grid = (B*H rows) * 4 d-chunks of 32. (unchanged)
// ---------------------------------------------------------------------------
__global__ __launch_bounds__(256) void k3_outproj(
    const float* __restrict__ ys_t,
    const float* __restrict__ ow, const float* __restrict__ ob,
    float* __restrict__ out)
{
    __shared__ float ysL[64][65];

    const int blk = blockIdx.x;
    const int row = blk >> 2;
    const int dc  = blk & 3;
    const int b = row >> 6, i = row & 63;
    const int t = threadIdx.x;
    const int w = t >> 6, j = t & 63;
    const int d0 = dc * 32 + w * 8;

    float acc[8];
    #pragma unroll
    for (int dd = 0; dd < 8; ++dd) acc[dd] = 0.f;

    for (int ch = 0; ch < 4; ++ch) {
        __syncthreads();
        for (int idx = t; idx < 64 * 64; idx += 256) {
            const int ee = idx >> 6, jj = idx & 63;
            ysL[ee][jj] = ys_t[(((size_t)(b * EE + ch * 64 + ee) * HH + i) << 6) + jj];
        }
        __syncthreads();
        for (int e64 = 0; e64 < 64; ++e64) {
            const float yv = ysL[e64][j];
            const int e = ch * 64 + e64;
            #pragma unroll
            for (int dd = 0; dd < 8; ++dd)
                acc[dd] = fmaf(ow[(d0 + dd) * EE + e], yv, acc[dd]);
        }
    }

    float* orow = out + (size_t)row * (WW * DM) + (size_t)j * DM + d0;
    #pragma unroll
    for (int dd = 0; dd < 8; ++dd) orow[dd] = acc[dd] + ob[d0 + dd];
}

extern "C" void kernel_launch(void* const* d_in, const int* in_sizes, int n_in,
                              void* d_out, int out_size, void* d_ws, size_t ws_size,
                              hipStream_t stream) {
    const float* x    = (const float*)d_in[0];
    const float* ipw  = (const float*)d_in[1];
    const float* ipb  = (const float*)d_in[2];
    const float* xpw  = (const float*)d_in[3];
    const float* xpb  = (const float*)d_in[4];
    const float* dtTw = (const float*)d_in[5];
    const float* dtTb = (const float*)d_in[6];
    const float* dtLw = (const float*)d_in[7];
    const float* dtLb = (const float*)d_in[8];
    const float* ATl  = (const float*)d_in[9];
    const float* ALl  = (const float*)d_in[10];
    const float* Dp   = (const float*)d_in[11];
    const float* ow   = (const float*)d_in[12];
    const float* ob   = (const float*)d_in[13];
    float* out = (float*)d_out;

    float* ws   = (float*)d_ws;
    float* u_t  = ws;
    float* dT_t = u_t  + (size_t)BB * EE * HW;
    float* dL_t = dT_t + (size_t)BB * EE * HW;
    float* ys_t = dL_t + (size_t)BB * EE * HW;
    float* Bm_t = ys_t + (size_t)BB * EE * HW;
    float* Cm_t = Bm_t + (size_t)BB * NN * HW;

    k1a_u<<<BB * HH * 8, 256, 0, stream>>>(x, ipw, ipb, u_t);
    k1b_proj<<<BB * HH, 512, 0, stream>>>(u_t, xpw, xpb, dtTw, dtTb, dtLw, dtLb,
                                          dT_t, dL_t, Bm_t, Cm_t);
    k2_scan<<<BB * EE, 256, 0, stream>>>(u_t, dT_t, dL_t, Bm_t, Cm_t,
                                         ATl, ALl, Dp, ys_t);
    k3_outproj<<<BB * HH * 4, 256, 0, stream>>>(ys_t, ow, ob, out);
}

// Round 6
// 177.120 us; speedup vs baseline: 1.3383x; 1.1927x over previous
//
#include <hip/hip_runtime.h>
#include <math.h>

// Problem constants
#define BB 2
#define HH 64
#define WW 64
#define DM 128
#define EE 256
#define NN 16
#define RR 8
#define HW (HH*WW)          // 4096

__device__ __forceinline__ float gelu_exact(float v) {
    return 0.5f * v * (1.f + erff(v * 0.70710678118654752440f));
}
__device__ __forceinline__ float softplus_f(float v) {
    return fmaxf(v, 0.f) + log1pf(__expf(-fabsf(v)));
}

// ---------------------------------------------------------------------------
// K1a: u = gelu(x@ipw^T + ipb) written transposed u_t[B,E,H,W].
// grid = (B*H rows) * 8 e-chunks of 32. block 256 thr. (unchanged)
// ---------------------------------------------------------------------------
__global__ __launch_bounds__(256) void k1a_u(
    const float* __restrict__ x,
    const float* __restrict__ ipw, const float* __restrict__ ipb,
    float* __restrict__ u_t)
{
    __shared__ float xs[64][129];

    const int blk = blockIdx.x;
    const int row = blk >> 3;            // b*64 + i
    const int ec  = blk & 7;
    const int b = row >> 6, i = row & 63;
    const int t = threadIdx.x;
    const int w = t >> 6, j = t & 63;

    const float* xrow = x + (size_t)row * (WW * DM);
    for (int idx = t; idx < WW * DM; idx += 256)
        xs[idx >> 7][idx & 127] = xrow[idx];
    __syncthreads();

    const int e0 = ec * 32 + w * 8;
    float acc[8];
    #pragma unroll
    for (int ee = 0; ee < 8; ++ee) acc[ee] = 0.f;

    for (int k = 0; k < DM; ++k) {
        const float xv = xs[j][k];
        #pragma unroll
        for (int ee = 0; ee < 8; ++ee)
            acc[ee] = fmaf(xv, ipw[(e0 + ee) * DM + k], acc[ee]);
    }
    #pragma unroll
    for (int ee = 0; ee < 8; ++ee) {
        const int e = e0 + ee;
        u_t[(((size_t)(b * EE + e) * HH + i) << 6) + j] = gelu_exact(acc[ee] + ipb[e]);
    }
}

// ---------------------------------------------------------------------------
// K1b1: dbc = u@xpw^T (+bias). grid = 128 rows x 8 c-groups = 1024 blocks,
// 256 thr = 4 waves. Block owns 6 channels c = 6*cg..6*cg+5; xpw slice in
// LDS (wave-uniform b128 broadcast reads); waves K-split e (4 x 64); u read
// from global coalesced. Cross-wave reduce via padded LDS tile + 1 barrier.
// Channels 16..47 -> Bm_t/Cm_t directly; channels 0..15 -> dbc_g (for k1b2).
// ---------------------------------------------------------------------------
__global__ __launch_bounds__(256) void k1b1_dbc(
    const float* __restrict__ u_t,
    const float* __restrict__ xpw, const float* __restrict__ xpb,
    float* __restrict__ dbc_g, float* __restrict__ Bm_t, float* __restrict__ Cm_t)
{
    __shared__ float xw[6][260];
    __shared__ float part[4][6][68];

    const int blk = blockIdx.x;
    const int cg = blk & 7;
    const int row = blk >> 3;            // b*64 + i
    const int b = row >> 6, i = row & 63;
    const int c0 = 6 * cg;
    const int t = threadIdx.x;
    const int w2 = t >> 6, j = t & 63;

    for (int idx = t; idx < 6 * 64; idx += 256) {
        const int cc = idx >> 6, e4 = idx & 63;
        *(float4*)&xw[cc][4 * e4] = ((const float4*)xpw)[(size_t)(c0 + cc) * 64 + e4];
    }
    __syncthreads();

    const float* ub = u_t + (((size_t)(b * EE)) << 12) + (i << 6) + j;
    const int ebase = 64 * w2;

    float acc[6] = {0.f, 0.f, 0.f, 0.f, 0.f, 0.f};
    for (int e4 = 0; e4 < 16; ++e4) {
        const int e = ebase + 4 * e4;
        const float u0 = ub[(size_t)(e + 0) << 12];
        const float u1 = ub[(size_t)(e + 1) << 12];
        const float u2 = ub[(size_t)(e + 2) << 12];
        const float u3 = ub[(size_t)(e + 3) << 12];
        #pragma unroll
        for (int cc = 0; cc < 6; ++cc) {
            const float4 wv = *(const float4*)&xw[cc][e];
            acc[cc] = fmaf(u0, wv.x, acc[cc]);
            acc[cc] = fmaf(u1, wv.y, acc[cc]);
            acc[cc] = fmaf(u2, wv.z, acc[cc]);
            acc[cc] = fmaf(u3, wv.w, acc[cc]);
        }
    }
    #pragma unroll
    for (int cc = 0; cc < 6; ++cc) part[w2][cc][j] = acc[cc];
    __syncthreads();

    for (int idx = t; idx < 6 * 64; idx += 256) {
        const int cc = idx >> 6, j2 = idx & 63;
        const int c = c0 + cc;
        const float s = ((part[0][cc][j2] + part[1][cc][j2]) +
                         (part[2][cc][j2] + part[3][cc][j2])) + xpb[c];
        if (c < 16) {
            dbc_g[((size_t)row * 16 + c) * 64 + j2] = s;
        } else if (c < 32) {
            const int n = c - 16;
            Bm_t[(((size_t)(b * NN + n) * HH + i) << 6) + j2] = s;
        } else {
            const int n = c - 32;
            Cm_t[(((size_t)(b * NN + n) * HH + i) << 6) + j2] = s;
        }
    }
}

// ---------------------------------------------------------------------------
// K1b2: deltaT/L = softplus(d@dtw^T + b). grid = 128 rows x 4 e-quarters
// = 512 blocks, 256 thr. dbc rows 0..15 staged in LDS; e wave-uniform so
// dtTw/dtLb reads are broadcast; coalesced stores.
// ---------------------------------------------------------------------------
__global__ __launch_bounds__(256) void k1b2_delta(
    const float* __restrict__ dbc_g,
    const float* __restrict__ dtTw, const float* __restrict__ dtTb,
    const float* __restrict__ dtLw, const float* __restrict__ dtLb,
    float* __restrict__ dT_t, float* __restrict__ dL_t)
{
    __shared__ float db[16][68];

    const int blk = blockIdx.x;
    const int eq = blk & 3;
    const int row = blk >> 2;            // b*64 + i
    const int b = row >> 6, i = row & 63;
    const int t = threadIdx.x;
    const int w2 = t >> 6, j = t & 63;

    for (int idx = t; idx < 16 * 64; idx += 256) {
        const int c = idx >> 6, j2 = idx & 63;
        db[c][j2] = dbc_g[((size_t)row * 16 + c) * 64 + j2];
    }
    __syncthreads();

    float dtv[8], dlv[8];
    #pragma unroll
    for (int r = 0; r < 8; ++r) { dtv[r] = db[r][j]; dlv[r] = db[8 + r][j]; }

    #pragma unroll 4
    for (int k = 0; k < 16; ++k) {
        const int e = 64 * eq + w2 + 4 * k;
        float sT = dtTb[e], sL = dtLb[e];
        #pragma unroll
        for (int r = 0; r < 8; ++r) {
            sT = fmaf(dtv[r], dtTw[e * RR + r], sT);
            sL = fmaf(dlv[r], dtLw[e * RR + r], sL);
        }
        dT_t[(((size_t)(b * EE + e) * HH + i) << 6) + j] = softplus_f(sT);
        dL_t[(((size_t)(b * EE + e) * HH + i) << 6) + j] = softplus_f(sL);
    }
}

// ---------------------------------------------------------------------------
// K2: wavefront scan. Block per (b,e): 256 thr = 4 waves. (unchanged)
// ---------------------------------------------------------------------------
__global__ __launch_bounds__(256) void k2_scan(
    const float* __restrict__ u_t, const float* __restrict__ dT_t,
    const float* __restrict__ dL_t, const float* __restrict__ Bm_t,
    const float* __restrict__ Cm_t, const float* __restrict__ ATl,
    const float* __restrict__ ALl, const float* __restrict__ Dp,
    float* __restrict__ ys_t)
{
    __shared__ float part[2][NN][68];

    const int be = blockIdx.x;           // b*256 + e
    const int b = be >> 8, e = be & 255;
    const int t = threadIdx.x;
    const int w = t >> 6, lane = t & 63;
    const int c = lane >> 4, jj = lane & 15;
    const int n = w * 4 + c;

    const float LOG2E = 1.44269504088896340736f;
    const float AT2 = -__expf(ATl[e * NN + n]) * LOG2E;
    const float AL2 = -__expf(ALl[e * NN + n]) * LOG2E;
    const float De = Dp[e];

    const float* dTp = dT_t + ((size_t)be << 12) + 4 * jj;
    const float* dLp = dL_t + ((size_t)be << 12) + 4 * jj;
    const float* up  = u_t  + ((size_t)be << 12) + 4 * jj;
    const float* bmp = Bm_t + ((size_t)(b * NN + n) << 12) + 4 * jj;
    const float* cmp = Cm_t + ((size_t)(b * NN + n) << 12) + 4 * jj;

    const int fcol = 16 * w + jj;
    const float* ufin = u_t + ((size_t)be << 12) + fcol;
    float* ysfin = ys_t + ((size_t)be << 12) + fcol;

    float h[4] = {0.f, 0.f, 0.f, 0.f};

    float4 dT4 = *(const float4*)dTp;
    float4 dL4 = *(const float4*)dLp;
    float4 u4  = *(const float4*)up;
    float4 bm4 = *(const float4*)bmp;
    float4 cm4 = *(const float4*)cmp;
    float  uf  = *ufin;

    for (int i = 0; i < HH; ++i) {
        const int ip = (i < HH - 1) ? (i + 1) : i;
        const float4 dT4n = *(const float4*)(dTp + (ip << 6));
        const float4 dL4n = *(const float4*)(dLp + (ip << 6));
        const float4 u4n  = *(const float4*)(up  + (ip << 6));
        const float4 bm4n = *(const float4*)(bmp + (ip << 6));
        const float4 cm4n = *(const float4*)(cmp + (ip << 6));
        const float  ufn  = ufin[ip << 6];

        const float dTv[4] = {dT4.x, dT4.y, dT4.z, dT4.w};
        const float dLv[4] = {dL4.x, dL4.y, dL4.z, dL4.w};
        const float uv[4]  = {u4.x,  u4.y,  u4.z,  u4.w};
        const float bmv[4] = {bm4.x, bm4.y, bm4.z, bm4.w};
        const float cmv[4] = {cm4.x, cm4.y, cm4.z, cm4.w};

        float cumA[4], cumB[4];
        {
            const float aT = exp2f(dTv[0] * AT2);
            const float aL = exp2f(dLv[0] * AL2);
            cumB[0] = fmaf(aT, h[0], (dTv[0] + dLv[0]) * bmv[0] * uv[0]);
            cumA[0] = aL;
        }
        #pragma unroll
        for (int k = 1; k < 4; ++k) {
            const float aT = exp2f(dTv[k] * AT2);
            const float aL = exp2f(dLv[k] * AL2);
            const float bk = fmaf(aT, h[k], (dTv[k] + dLv[k]) * bmv[k] * uv[k]);
            cumB[k] = fmaf(aL, cumB[k - 1], bk);
            cumA[k] = aL * cumA[k - 1];
        }
        float Ag = cumA[3], Bg = cumB[3];
        #pragma unroll
        for (int s = 1; s < 8; s <<= 1) {
            const float uA = __shfl_up(Ag, (unsigned)s, 64);
            const float uB = __shfl_up(Bg, (unsigned)s, 64);
            if (jj >= s) { Bg = fmaf(Ag, uB, Bg); Ag *= uA; }
        }
        {
            const float uB = __shfl_up(Bg, 8u, 64);
            if (jj >= 8) Bg = fmaf(Ag, uB, Bg);
        }
        float pB = __shfl_up(Bg, 1u, 64);
        if (jj == 0) pB = 0.f;

        float g[4];
        #pragma unroll
        for (int k = 0; k < 4; ++k) {
            const float hh = fmaf(cumA[k], pB, cumB[k]);
            h[k] = hh;
            g[k] = hh * cmv[k];
        }

        const int buf = i & 1;
        *(float4*)&part[buf][n][4 * jj] = make_float4(g[0], g[1], g[2], g[3]);
        __syncthreads();

        float p0 = part[buf][c +  0][fcol];
        float p1 = part[buf][c +  4][fcol];
        float p2 = part[buf][c +  8][fcol];
        float p3 = part[buf][c + 12][fcol];
        float ps = (p0 + p1) + (p2 + p3);
        ps += __shfl_xor(ps, 16, 64);
        ps += __shfl_xor(ps, 32, 64);
        if (c == 0) {
            ysfin[i << 6] = gelu_exact(fmaf(uf, De, ps));
        }

        dT4 = dT4n; dL4 = dL4n; u4 = u4n; bm4 = bm4n; cm4 = cm4n; uf = ufn;
    }
}

// ---------------------------------------------------------------------------
// K3: out projection. grid = (B*H rows) * 4 d-chunks of 32. (unchanged)
// ---------------------------------------------------------------------------
__global__ __launch_bounds__(256) void k3_outproj(
    const float* __restrict__ ys_t,
    const float* __restrict__ ow, const float* __restrict__ ob,
    float* __restrict__ out)
{
    __shared__ float ysL[64][65];

    const int blk = blockIdx.x;
    const int row = blk >> 2;
    const int dc  = blk & 3;
    const int b = row >> 6, i = row & 63;
    const int t = threadIdx.x;
    const int w = t >> 6, j = t & 63;
    const int d0 = dc * 32 + w * 8;

    float acc[8];
    #pragma unroll
    for (int dd = 0; dd < 8; ++dd) acc[dd] = 0.f;

    for (int ch = 0; ch < 4; ++ch) {
        __syncthreads();
        for (int idx = t; idx < 64 * 64; idx += 256) {
            const int ee = idx >> 6, jj = idx & 63;
            ysL[ee][jj] = ys_t[(((size_t)(b * EE + ch * 64 + ee) * HH + i) << 6) + jj];
        }
        __syncthreads();
        for (int e64 = 0; e64 < 64; ++e64) {
            const float yv = ysL[e64][j];
            const int e = ch * 64 + e64;
            #pragma unroll
            for (int dd = 0; dd < 8; ++dd)
                acc[dd] = fmaf(ow[(d0 + dd) * EE + e], yv, acc[dd]);
        }
    }

    float* orow = out + (size_t)row * (WW * DM) + (size_t)j * DM + d0;
    #pragma unroll
    for (int dd = 0; dd < 8; ++dd) orow[dd] = acc[dd] + ob[d0 + dd];
}

extern "C" void kernel_launch(void* const* d_in, const int* in_sizes, int n_in,
                              void* d_out, int out_size, void* d_ws, size_t ws_size,
                              hipStream_t stream) {
    const float* x    = (const float*)d_in[0];
    const float* ipw  = (const float*)d_in[1];
    const float* ipb  = (const float*)d_in[2];
    const float* xpw  = (const float*)d_in[3];
    const float* xpb  = (const float*)d_in[4];
    const float* dtTw = (const float*)d_in[5];
    const float* dtTb = (const float*)d_in[6];
    const float* dtLw = (const float*)d_in[7];
    const float* dtLb = (const float*)d_in[8];
    const float* ATl  = (const float*)d_in[9];
    const float* ALl  = (const float*)d_in[10];
    const float* Dp   = (const float*)d_in[11];
    const float* ow   = (const float*)d_in[12];
    const float* ob   = (const float*)d_in[13];
    float* out = (float*)d_out;

    float* ws    = (float*)d_ws;
    float* u_t   = ws;
    float* dT_t  = u_t  + (size_t)BB * EE * HW;
    float* dL_t  = dT_t + (size_t)BB * EE * HW;
    float* ys_t  = dL_t + (size_t)BB * EE * HW;
    float* Bm_t  = ys_t + (size_t)BB * EE * HW;
    float* Cm_t  = Bm_t + (size_t)BB * NN * HW;
    float* dbc_g = Cm_t + (size_t)BB * NN * HW;   // [128][16][64]

    k1a_u<<<BB * HH * 8, 256, 0, stream>>>(x, ipw, ipb, u_t);
    k1b1_dbc<<<BB * HH * 8, 256, 0, stream>>>(u_t, xpw, xpb, dbc_g, Bm_t, Cm_t);
    k1b2_delta<<<BB * HH * 4, 256, 0, stream>>>(dbc_g, dtTw, dtTb, dtLw, dtLb,
                                                dT_t, dL_t);
    k2_scan<<<BB * EE, 256, 0, stream>>>(u_t, dT_t, dL_t, Bm_t, Cm_t,
                                         ATl, ALl, Dp, ys_t);
    k3_outproj<<<BB * HH * 4, 256, 0, stream>>>(ys_t, ow, ob, out);
}

// Round 7
// 142.175 us; speedup vs baseline: 1.6672x; 1.2458x over previous
//
#include <hip/hip_runtime.h>
#include <math.h>

// Problem constants
#define BB 2
#define HH 64
#define WW 64
#define DM 128
#define EE 256
#define NN 16
#define RR 8
#define HW (HH*WW)          // 4096

__device__ __forceinline__ float gelu_exact(float v) {
    return 0.5f * v * (1.f + erff(v * 0.70710678118654752440f));
}
__device__ __forceinline__ float softplus_f(float v) {
    return fmaxf(v, 0.f) + log1pf(__expf(-fabsf(v)));
}

// ---------------------------------------------------------------------------
// K1a: u = gelu(x@ipw^T + ipb) -> u_t[B,E,H,W]. grid = 128 rows x 8 e-chunks.
// w forced scalar via readfirstlane so ipw reads compile to s_loads.
// ---------------------------------------------------------------------------
__global__ __launch_bounds__(256) void k1a_u(
    const float* __restrict__ x,
    const float* __restrict__ ipw, const float* __restrict__ ipb,
    float* __restrict__ u_t)
{
    __shared__ float xs[64][129];

    const int blk = blockIdx.x;
    const int row = blk >> 3;            // b*64 + i
    const int ec  = blk & 7;
    const int b = row >> 6, i = row & 63;
    const int t = threadIdx.x;
    const int w = __builtin_amdgcn_readfirstlane(t >> 6);
    const int j = t & 63;

    const float* xrow = x + (size_t)row * (WW * DM);
    for (int idx = t; idx < WW * DM; idx += 256)
        xs[idx >> 7][idx & 127] = xrow[idx];
    __syncthreads();

    const int e0 = ec * 32 + w * 8;
    float acc[8];
    #pragma unroll
    for (int ee = 0; ee < 8; ++ee) acc[ee] = 0.f;

    for (int k = 0; k < DM; ++k) {
        const float xv = xs[j][k];
        #pragma unroll
        for (int ee = 0; ee < 8; ++ee)
            acc[ee] = fmaf(xv, ipw[(e0 + ee) * DM + k], acc[ee]);
    }
    #pragma unroll
    for (int ee = 0; ee < 8; ++ee) {
        const int e = e0 + ee;
        u_t[(((size_t)(b * EE + e) * HH + i) << 6) + j] = gelu_exact(acc[ee] + ipb[e]);
    }
}

// ---------------------------------------------------------------------------
// K1b1: dbc = u@xpw^T (+bias). 1024 blocks, 4 waves, K-split + LDS reduce.
// ---------------------------------------------------------------------------
__global__ __launch_bounds__(256) void k1b1_dbc(
    const float* __restrict__ u_t,
    const float* __restrict__ xpw, const float* __restrict__ xpb,
    float* __restrict__ dbc_g, float* __restrict__ Bm_t, float* __restrict__ Cm_t)
{
    __shared__ float xw[6][260];
    __shared__ float part[4][6][68];

    const int blk = blockIdx.x;
    const int cg = blk & 7;
    const int row = blk >> 3;            // b*64 + i
    const int b = row >> 6, i = row & 63;
    const int c0 = 6 * cg;
    const int t = threadIdx.x;
    const int w2 = __builtin_amdgcn_readfirstlane(t >> 6);
    const int j = t & 63;

    for (int idx = t; idx < 6 * 64; idx += 256) {
        const int cc = idx >> 6, e4 = idx & 63;
        *(float4*)&xw[cc][4 * e4] = ((const float4*)xpw)[(size_t)(c0 + cc) * 64 + e4];
    }
    __syncthreads();

    const float* ub = u_t + (((size_t)(b * EE)) << 12) + (i << 6) + j;
    const int ebase = 64 * w2;

    float acc[6] = {0.f, 0.f, 0.f, 0.f, 0.f, 0.f};
    for (int e4 = 0; e4 < 16; ++e4) {
        const int e = ebase + 4 * e4;
        const float u0 = ub[(size_t)(e + 0) << 12];
        const float u1 = ub[(size_t)(e + 1) << 12];
        const float u2 = ub[(size_t)(e + 2) << 12];
        const float u3 = ub[(size_t)(e + 3) << 12];
        #pragma unroll
        for (int cc = 0; cc < 6; ++cc) {
            const float4 wv = *(const float4*)&xw[cc][e];
            acc[cc] = fmaf(u0, wv.x, acc[cc]);
            acc[cc] = fmaf(u1, wv.y, acc[cc]);
            acc[cc] = fmaf(u2, wv.z, acc[cc]);
            acc[cc] = fmaf(u3, wv.w, acc[cc]);
        }
    }
    #pragma unroll
    for (int cc = 0; cc < 6; ++cc) part[w2][cc][j] = acc[cc];
    __syncthreads();

    for (int idx = t; idx < 6 * 64; idx += 256) {
        const int cc = idx >> 6, j2 = idx & 63;
        const int c = c0 + cc;
        const float s = ((part[0][cc][j2] + part[1][cc][j2]) +
                         (part[2][cc][j2] + part[3][cc][j2])) + xpb[c];
        if (c < 16) {
            dbc_g[((size_t)row * 16 + c) * 64 + j2] = s;
        } else if (c < 32) {
            const int n = c - 16;
            Bm_t[(((size_t)(b * NN + n) * HH + i) << 6) + j2] = s;
        } else {
            const int n = c - 32;
            Cm_t[(((size_t)(b * NN + n) * HH + i) << 6) + j2] = s;
        }
    }
}

// ---------------------------------------------------------------------------
// K1b2: deltaT/L = softplus(d@dtw^T + b). 512 blocks. e scalar -> s_loads.
// ---------------------------------------------------------------------------
__global__ __launch_bounds__(256) void k1b2_delta(
    const float* __restrict__ dbc_g,
    const float* __restrict__ dtTw, const float* __restrict__ dtTb,
    const float* __restrict__ dtLw, const float* __restrict__ dtLb,
    float* __restrict__ dT_t, float* __restrict__ dL_t)
{
    __shared__ float db[16][68];

    const int blk = blockIdx.x;
    const int eq = blk & 3;
    const int row = blk >> 2;            // b*64 + i
    const int b = row >> 6, i = row & 63;
    const int t = threadIdx.x;
    const int w2 = __builtin_amdgcn_readfirstlane(t >> 6);
    const int j = t & 63;

    for (int idx = t; idx < 16 * 64; idx += 256) {
        const int c = idx >> 6, j2 = idx & 63;
        db[c][j2] = dbc_g[((size_t)row * 16 + c) * 64 + j2];
    }
    __syncthreads();

    float dtv[8], dlv[8];
    #pragma unroll
    for (int r = 0; r < 8; ++r) { dtv[r] = db[r][j]; dlv[r] = db[8 + r][j]; }

    #pragma unroll 4
    for (int k = 0; k < 16; ++k) {
        const int e = 64 * eq + w2 + 4 * k;
        float sT = dtTb[e], sL = dtLb[e];
        #pragma unroll
        for (int r = 0; r < 8; ++r) {
            sT = fmaf(dtv[r], dtTw[e * RR + r], sT);
            sL = fmaf(dlv[r], dtLw[e * RR + r], sL);
        }
        dT_t[(((size_t)(b * EE + e) * HH + i) << 6) + j] = softplus_f(sT);
        dL_t[(((size_t)(b * EE + e) * HH + i) << 6) + j] = softplus_f(sL);
    }
}

// ---------------------------------------------------------------------------
// K2a: wavefront scan, two-pass. Block per (b,e): 4 waves, NO LDS, NO barrier.
// Wave w owns channels n = 4w+c; after scan, in-register cross-c reduce
// (shfl_xor 16/32), then each lane stores one col of the 4-channel partial:
// wave0 -> ys_t (as p0), waves1-3 -> pscr planes.
// ---------------------------------------------------------------------------
__global__ __launch_bounds__(256) void k2a_scan(
    const float* __restrict__ u_t, const float* __restrict__ dT_t,
    const float* __restrict__ dL_t, const float* __restrict__ Bm_t,
    const float* __restrict__ Cm_t, const float* __restrict__ ATl,
    const float* __restrict__ ALl,
    float* __restrict__ ys_t, float* __restrict__ pscr)
{
    const int be = blockIdx.x;           // b*256 + e
    const int b = be >> 8, e = be & 255;
    const int t = threadIdx.x;
    const int w = __builtin_amdgcn_readfirstlane(t >> 6);
    const int lane = t & 63;
    const int c = lane >> 4, jj = lane & 15;
    const int n = w * 4 + c;

    const float LOG2E = 1.44269504088896340736f;
    const float AT2 = -__expf(ATl[e * NN + n]) * LOG2E;
    const float AL2 = -__expf(ALl[e * NN + n]) * LOG2E;

    const float* dTp = dT_t + ((size_t)be << 12) + 4 * jj;
    const float* dLp = dL_t + ((size_t)be << 12) + 4 * jj;
    const float* up  = u_t  + ((size_t)be << 12) + 4 * jj;
    const float* bmp = Bm_t + ((size_t)(b * NN + n) << 12) + 4 * jj;
    const float* cmp = Cm_t + ((size_t)(b * NN + n) << 12) + 4 * jj;

    float* pg = (w == 0)
        ? (ys_t + ((size_t)be << 12))
        : (pscr + ((size_t)((w - 1) * (BB * EE) + be) << 12));

    float h[4] = {0.f, 0.f, 0.f, 0.f};

    float4 dT4 = *(const float4*)dTp;
    float4 dL4 = *(const float4*)dLp;
    float4 u4  = *(const float4*)up;
    float4 bm4 = *(const float4*)bmp;
    float4 cm4 = *(const float4*)cmp;

    for (int i = 0; i < HH; ++i) {
        const int ip = (i < HH - 1) ? (i + 1) : i;
        const float4 dT4n = *(const float4*)(dTp + (ip << 6));
        const float4 dL4n = *(const float4*)(dLp + (ip << 6));
        const float4 u4n  = *(const float4*)(up  + (ip << 6));
        const float4 bm4n = *(const float4*)(bmp + (ip << 6));
        const float4 cm4n = *(const float4*)(cmp + (ip << 6));

        const float dTv[4] = {dT4.x, dT4.y, dT4.z, dT4.w};
        const float dLv[4] = {dL4.x, dL4.y, dL4.z, dL4.w};
        const float uv[4]  = {u4.x,  u4.y,  u4.z,  u4.w};
        const float bmv[4] = {bm4.x, bm4.y, bm4.z, bm4.w};
        const float cmv[4] = {cm4.x, cm4.y, cm4.z, cm4.w};

        float cumA[4], cumB[4];
        {
            const float aT = exp2f(dTv[0] * AT2);
            const float aL = exp2f(dLv[0] * AL2);
            cumB[0] = fmaf(aT, h[0], (dTv[0] + dLv[0]) * bmv[0] * uv[0]);
            cumA[0] = aL;
        }
        #pragma unroll
        for (int k = 1; k < 4; ++k) {
            const float aT = exp2f(dTv[k] * AT2);
            const float aL = exp2f(dLv[k] * AL2);
            const float bk = fmaf(aT, h[k], (dTv[k] + dLv[k]) * bmv[k] * uv[k]);
            cumB[k] = fmaf(aL, cumB[k - 1], bk);
            cumA[k] = aL * cumA[k - 1];
        }
        float Ag = cumA[3], Bg = cumB[3];
        #pragma unroll
        for (int s = 1; s < 8; s <<= 1) {
            const float uA = __shfl_up(Ag, (unsigned)s, 64);
            const float uB = __shfl_up(Bg, (unsigned)s, 64);
            if (jj >= s) { Bg = fmaf(Ag, uB, Bg); Ag *= uA; }
        }
        {
            const float uB = __shfl_up(Bg, 8u, 64);
            if (jj >= 8) Bg = fmaf(Ag, uB, Bg);
        }
        float pB = __shfl_up(Bg, 1u, 64);
        if (jj == 0) pB = 0.f;

        float g[4];
        #pragma unroll
        for (int k = 0; k < 4; ++k) {
            const float hh = fmaf(cumA[k], pB, cumB[k]);
            h[k] = hh;
            g[k] = hh * cmv[k];
        }

        // terminal cross-channel reduce (off h critical path)
        #pragma unroll
        for (int k = 0; k < 4; ++k) {
            g[k] += __shfl_xor(g[k], 16, 64);
            g[k] += __shfl_xor(g[k], 32, 64);
        }
        // lane (c,jj) stores col 4*jj+c -> full 64-col coalesced store
        const float gout = (c == 0) ? g[0] : (c == 1) ? g[1] : (c == 2) ? g[2] : g[3];
        pg[(i << 6) + 4 * jj + c] = gout;

        dT4 = dT4n; dL4 = dL4n; u4 = u4n; bm4 = bm4n; cm4 = cm4n;
    }
}

// ---------------------------------------------------------------------------
// K2b: ys = gelu(p0+p1+p2+p3 + u*D). 2048 blocks x 256 thr, float4/thread.
// p0 lives in ys_t (written by k2a wave0); in-place update.
// ---------------------------------------------------------------------------
__global__ __launch_bounds__(256) void k2b_fin(
    const float* __restrict__ u_t, const float* __restrict__ pscr,
    const float* __restrict__ Dp, float* __restrict__ ys_t)
{
    const int blk = blockIdx.x;
    const int be = blk >> 2, q = blk & 3;
    const int e = be & 255;
    const float De = Dp[e];
    const size_t base = ((size_t)be << 12) + (q << 10) + (threadIdx.x << 2);
    const size_t plane = ((size_t)(BB * EE)) << 12;

    float4 s        = *(const float4*)(ys_t + base);
    const float4 a1 = *(const float4*)(pscr + base);
    const float4 a2 = *(const float4*)(pscr + plane + base);
    const float4 a3 = *(const float4*)(pscr + 2 * plane + base);
    const float4 uu = *(const float4*)(u_t + base);

    s.x = gelu_exact(fmaf(uu.x, De, ((s.x + a1.x) + (a2.x + a3.x))));
    s.y = gelu_exact(fmaf(uu.y, De, ((s.y + a1.y) + (a2.y + a3.y))));
    s.z = gelu_exact(fmaf(uu.z, De, ((s.z + a1.z) + (a2.z + a3.z))));
    s.w = gelu_exact(fmaf(uu.w, De, ((s.w + a1.w) + (a2.w + a3.w))));

    *(float4*)(ys_t + base) = s;
}

// ---------------------------------------------------------------------------
// K3: out projection. grid = 128 rows x 4 d-chunks. w scalar -> ow s_loads.
// ---------------------------------------------------------------------------
__global__ __launch_bounds__(256) void k3_outproj(
    const float* __restrict__ ys_t,
    const float* __restrict__ ow, const float* __restrict__ ob,
    float* __restrict__ out)
{
    __shared__ float ysL[64][65];

    const int blk = blockIdx.x;
    const int row = blk >> 2;
    const int dc  = blk & 3;
    const int b = row >> 6, i = row & 63;
    const int t = threadIdx.x;
    const int w = __builtin_amdgcn_readfirstlane(t >> 6);
    const int j = t & 63;
    const int d0 = dc * 32 + w * 8;

    float acc[8];
    #pragma unroll
    for (int dd = 0; dd < 8; ++dd) acc[dd] = 0.f;

    for (int ch = 0; ch < 4; ++ch) {
        __syncthreads();
        for (int idx = t; idx < 64 * 64; idx += 256) {
            const int ee = idx >> 6, jj = idx & 63;
            ysL[ee][jj] = ys_t[(((size_t)(b * EE + ch * 64 + ee) * HH + i) << 6) + jj];
        }
        __syncthreads();
        for (int e64 = 0; e64 < 64; ++e64) {
            const float yv = ysL[e64][j];
            const int e = ch * 64 + e64;
            #pragma unroll
            for (int dd = 0; dd < 8; ++dd)
                acc[dd] = fmaf(ow[(d0 + dd) * EE + e], yv, acc[dd]);
        }
    }

    float* orow = out + (size_t)row * (WW * DM) + (size_t)j * DM + d0;
    #pragma unroll
    for (int dd = 0; dd < 8; ++dd) orow[dd] = acc[dd] + ob[d0 + dd];
}

extern "C" void kernel_launch(void* const* d_in, const int* in_sizes, int n_in,
                              void* d_out, int out_size, void* d_ws, size_t ws_size,
                              hipStream_t stream) {
    const float* x    = (const float*)d_in[0];
    const float* ipw  = (const float*)d_in[1];
    const float* ipb  = (const float*)d_in[2];
    const float* xpw  = (const float*)d_in[3];
    const float* xpb  = (const float*)d_in[4];
    const float* dtTw = (const float*)d_in[5];
    const float* dtTb = (const float*)d_in[6];
    const float* dtLw = (const float*)d_in[7];
    const float* dtLb = (const float*)d_in[8];
    const float* ATl  = (const float*)d_in[9];
    const float* ALl  = (const float*)d_in[10];
    const float* Dp   = (const float*)d_in[11];
    const float* ow   = (const float*)d_in[12];
    const float* ob   = (const float*)d_in[13];
    float* out = (float*)d_out;

    float* ws    = (float*)d_ws;
    float* u_t   = ws;
    float* dT_t  = u_t  + (size_t)BB * EE * HW;
    float* dL_t  = dT_t + (size_t)BB * EE * HW;
    float* ys_t  = dL_t + (size_t)BB * EE * HW;
    float* Bm_t  = ys_t + (size_t)BB * EE * HW;
    float* Cm_t  = Bm_t + (size_t)BB * NN * HW;
    float* dbc_g = Cm_t + (size_t)BB * NN * HW;   // [128][16][64]
    float* pscr  = dbc_g + (size_t)BB * HH * NN * WW; // 3 planes of [B,E,H,W]

    k1a_u<<<BB * HH * 8, 256, 0, stream>>>(x, ipw, ipb, u_t);
    k1b1_dbc<<<BB * HH * 8, 256, 0, stream>>>(u_t, xpw, xpb, dbc_g, Bm_t, Cm_t);
    k1b2_delta<<<BB * HH * 4, 256, 0, stream>>>(dbc_g, dtTw, dtTb, dtLw, dtLb,
                                                dT_t, dL_t);
    k2a_scan<<<BB * EE, 256, 0, stream>>>(u_t, dT_t, dL_t, Bm_t, Cm_t,
                                          ATl, ALl, ys_t, pscr);
    k2b_fin<<<BB * EE * 4, 256, 0, stream>>>(u_t, pscr, Dp, ys_t);
    k3_outproj<<<BB * HH * 4, 256, 0, stream>>>(ys_t, ow, ob, out);
}

// Round 9
// 134.846 us; speedup vs baseline: 1.7578x; 1.0544x over previous
//
#include <hip/hip_runtime.h>
#include <math.h>

// Problem constants
#define BB 2
#define HH 64
#define WW 64
#define DM 128
#define EE 256
#define NN 16
#define RR 8
#define HW (HH*WW)          // 4096

__device__ __forceinline__ float gelu_exact(float v) {
    return 0.5f * v * (1.f + erff(v * 0.70710678118654752440f));
}
__device__ __forceinline__ float softplus_f(float v) {
    return fmaxf(v, 0.f) + log1pf(__expf(-fabsf(v)));
}

// DPP row_shr within 16-lane rows: lane L gets lane L-S (same row).
// old = 0 so invalid lanes (jj < S) read 0 under EITHER bound_ctrl
// convention (0 is the additive identity for the B-chain; the A-chain
// masks explicitly with a cndmask). Pure VALU, no LDS pipe.
template<int S>
__device__ __forceinline__ float dpp_shr0(float x) {
    return __int_as_float(__builtin_amdgcn_update_dpp(
        0, __float_as_int(x), 0x110 | S, 0xF, 0xF, false));
}

// ---------------------------------------------------------------------------
// K1a: u = gelu(x@ipw^T + ipb) -> u_t[B,E,H,W]. grid = 128 rows x 8 e-chunks.
// ---------------------------------------------------------------------------
__global__ __launch_bounds__(256) void k1a_u(
    const float* __restrict__ x,
    const float* __restrict__ ipw, const float* __restrict__ ipb,
    float* __restrict__ u_t)
{
    __shared__ float xs[64][129];

    const int blk = blockIdx.x;
    const int row = blk >> 3;            // b*64 + i
    const int ec  = blk & 7;
    const int b = row >> 6, i = row & 63;
    const int t = threadIdx.x;
    const int w = __builtin_amdgcn_readfirstlane(t >> 6);
    const int j = t & 63;

    const float* xrow = x + (size_t)row * (WW * DM);
    for (int idx = t; idx < WW * DM; idx += 256)
        xs[idx >> 7][idx & 127] = xrow[idx];
    __syncthreads();

    const int e0 = ec * 32 + w * 8;
    float acc[8];
    #pragma unroll
    for (int ee = 0; ee < 8; ++ee) acc[ee] = 0.f;

    for (int k = 0; k < DM; ++k) {
        const float xv = xs[j][k];
        #pragma unroll
        for (int ee = 0; ee < 8; ++ee)
            acc[ee] = fmaf(xv, ipw[(e0 + ee) * DM + k], acc[ee]);
    }
    #pragma unroll
    for (int ee = 0; ee < 8; ++ee) {
        const int e = e0 + ee;
        u_t[(((size_t)(b * EE + e) * HH + i) << 6) + j] = gelu_exact(acc[ee] + ipb[e]);
    }
}

// ---------------------------------------------------------------------------
// K1b1: dbc = u@xpw^T (+bias). 1024 blocks, 4 waves, K-split + LDS reduce.
// ---------------------------------------------------------------------------
__global__ __launch_bounds__(256) void k1b1_dbc(
    const float* __restrict__ u_t,
    const float* __restrict__ xpw, const float* __restrict__ xpb,
    float* __restrict__ dbc_g, float* __restrict__ Bm_t, float* __restrict__ Cm_t)
{
    __shared__ float xw[6][260];
    __shared__ float part[4][6][68];

    const int blk = blockIdx.x;
    const int cg = blk & 7;
    const int row = blk >> 3;            // b*64 + i
    const int b = row >> 6, i = row & 63;
    const int c0 = 6 * cg;
    const int t = threadIdx.x;
    const int w2 = __builtin_amdgcn_readfirstlane(t >> 6);
    const int j = t & 63;

    for (int idx = t; idx < 6 * 64; idx += 256) {
        const int cc = idx >> 6, e4 = idx & 63;
        *(float4*)&xw[cc][4 * e4] = ((const float4*)xpw)[(size_t)(c0 + cc) * 64 + e4];
    }
    __syncthreads();

    const float* ub = u_t + (((size_t)(b * EE)) << 12) + (i << 6) + j;
    const int ebase = 64 * w2;

    float acc[6] = {0.f, 0.f, 0.f, 0.f, 0.f, 0.f};
    for (int e4 = 0; e4 < 16; ++e4) {
        const int e = ebase + 4 * e4;
        const float u0 = ub[(size_t)(e + 0) << 12];
        const float u1 = ub[(size_t)(e + 1) << 12];
        const float u2 = ub[(size_t)(e + 2) << 12];
        const float u3 = ub[(size_t)(e + 3) << 12];
        #pragma unroll
        for (int cc = 0; cc < 6; ++cc) {
            const float4 wv = *(const float4*)&xw[cc][e];
            acc[cc] = fmaf(u0, wv.x, acc[cc]);
            acc[cc] = fmaf(u1, wv.y, acc[cc]);
            acc[cc] = fmaf(u2, wv.z, acc[cc]);
            acc[cc] = fmaf(u3, wv.w, acc[cc]);
        }
    }
    #pragma unroll
    for (int cc = 0; cc < 6; ++cc) part[w2][cc][j] = acc[cc];
    __syncthreads();

    for (int idx = t; idx < 6 * 64; idx += 256) {
        const int cc = idx >> 6, j2 = idx & 63;
        const int c = c0 + cc;
        const float s = ((part[0][cc][j2] + part[1][cc][j2]) +
                         (part[2][cc][j2] + part[3][cc][j2])) + xpb[c];
        if (c < 16) {
            dbc_g[((size_t)row * 16 + c) * 64 + j2] = s;
        } else if (c < 32) {
            const int n = c - 16;
            Bm_t[(((size_t)(b * NN + n) * HH + i) << 6) + j2] = s;
        } else {
            const int n = c - 32;
            Cm_t[(((size_t)(b * NN + n) * HH + i) << 6) + j2] = s;
        }
    }
}

// ---------------------------------------------------------------------------
// K1b2: deltaT/L = softplus(d@dtw^T + b). 512 blocks. e scalar -> s_loads.
// ---------------------------------------------------------------------------
__global__ __launch_bounds__(256) void k1b2_delta(
    const float* __restrict__ dbc_g,
    const float* __restrict__ dtTw, const float* __restrict__ dtTb,
    const float* __restrict__ dtLw, const float* __restrict__ dtLb,
    float* __restrict__ dT_t, float* __restrict__ dL_t)
{
    __shared__ float db[16][68];

    const int blk = blockIdx.x;
    const int eq = blk & 3;
    const int row = blk >> 2;            // b*64 + i
    const int b = row >> 6, i = row & 63;
    const int t = threadIdx.x;
    const int w2 = __builtin_amdgcn_readfirstlane(t >> 6);
    const int j = t & 63;

    for (int idx = t; idx < 16 * 64; idx += 256) {
        const int c = idx >> 6, j2 = idx & 63;
        db[c][j2] = dbc_g[((size_t)row * 16 + c) * 64 + j2];
    }
    __syncthreads();

    float dtv[8], dlv[8];
    #pragma unroll
    for (int r = 0; r < 8; ++r) { dtv[r] = db[r][j]; dlv[r] = db[8 + r][j]; }

    #pragma unroll 4
    for (int k = 0; k < 16; ++k) {
        const int e = 64 * eq + w2 + 4 * k;
        float sT = dtTb[e], sL = dtLb[e];
        #pragma unroll
        for (int r = 0; r < 8; ++r) {
            sT = fmaf(dtv[r], dtTw[e * RR + r], sT);
            sL = fmaf(dlv[r], dtLw[e * RR + r], sL);
        }
        dT_t[(((size_t)(b * EE + e) * HH + i) << 6) + j] = softplus_f(sT);
        dL_t[(((size_t)(b * EE + e) * HH + i) << 6) + j] = softplus_f(sL);
    }
}

// ---------------------------------------------------------------------------
// K2a: wavefront scan. Block per (b,e): 4 waves. Lane (c = lane>>4,
// jj = lane&15): channel n = 4w+c, cols 4jj..4jj+3. Scan layers + prefix
// shift via DPP row_shr with old=0 (convention-proof; only the A-chain needs
// an explicit jj>=s mask). Terminal cross-channel reduce via shfl_xor
// (off the h critical path). Distance-2 prefetch, unroll-2 row loop.
// Wave0 partial -> ys_t, waves 1-3 -> pscr planes (k2b finalizes).
// ---------------------------------------------------------------------------
struct RowRegs { float4 dT, dL, u, bm, cm; };

__device__ __forceinline__ RowRegs row_load(
    const float* dTp, const float* dLp, const float* up,
    const float* bmp, const float* cmp, int i)
{
    RowRegs r;
    const int off = i << 6;
    r.dT = *(const float4*)(dTp + off);
    r.dL = *(const float4*)(dLp + off);
    r.u  = *(const float4*)(up  + off);
    r.bm = *(const float4*)(bmp + off);
    r.cm = *(const float4*)(cmp + off);
    return r;
}

__device__ __forceinline__ float row_scan(
    const RowRegs& r, float AT2, float AL2, float* h, int c, int jj)
{
    const float dTv[4] = {r.dT.x, r.dT.y, r.dT.z, r.dT.w};
    const float dLv[4] = {r.dL.x, r.dL.y, r.dL.z, r.dL.w};
    const float uv[4]  = {r.u.x,  r.u.y,  r.u.z,  r.u.w};
    const float bmv[4] = {r.bm.x, r.bm.y, r.bm.z, r.bm.w};
    const float cmv[4] = {r.cm.x, r.cm.y, r.cm.z, r.cm.w};

    // local inclusive scan over this lane's 4 cols
    float cumA[4], cumB[4];
    {
        const float aT = exp2f(dTv[0] * AT2);
        cumA[0] = exp2f(dLv[0] * AL2);
        cumB[0] = fmaf(aT, h[0], (dTv[0] + dLv[0]) * bmv[0] * uv[0]);
    }
    #pragma unroll
    for (int k = 1; k < 4; ++k) {
        const float aT = exp2f(dTv[k] * AT2);
        const float aL = exp2f(dLv[k] * AL2);
        const float bk = fmaf(aT, h[k], (dTv[k] + dLv[k]) * bmv[k] * uv[k]);
        cumB[k] = fmaf(aL, cumB[k - 1], bk);
        cumA[k] = aL * cumA[k - 1];
    }

    // 16-lane segmented Hillis-Steele on aggregates — all DPP (VALU).
    // uB invalid lanes read 0 = additive identity (no mask needed);
    // uA masked explicitly (multiplicative identity 1).
    float Ag = cumA[3], Bg = cumB[3];
    { const float uA = dpp_shr0<1>(Ag), uB = dpp_shr0<1>(Bg);
      Bg = fmaf(Ag, uB, Bg); Ag *= (jj >= 1) ? uA : 1.f; }
    { const float uA = dpp_shr0<2>(Ag), uB = dpp_shr0<2>(Bg);
      Bg = fmaf(Ag, uB, Bg); Ag *= (jj >= 2) ? uA : 1.f; }
    { const float uA = dpp_shr0<4>(Ag), uB = dpp_shr0<4>(Bg);
      Bg = fmaf(Ag, uB, Bg); Ag *= (jj >= 4) ? uA : 1.f; }
    { const float uB = dpp_shr0<8>(Bg);
      Bg = fmaf(Ag, uB, Bg); }              // Ag not needed afterward
    const float pB = dpp_shr0<1>(Bg);        // exclusive prefix; jj==0 -> 0

    float g[4];
    #pragma unroll
    for (int k = 0; k < 4; ++k) {
        h[k] = fmaf(cumA[k], pB, cumB[k]);
        g[k] = h[k] * cmv[k];
    }
    // terminal cross-channel reduce over c = lane>>4 (off critical path)
    #pragma unroll
    for (int k = 0; k < 4; ++k) {
        g[k] += __shfl_xor(g[k], 16, 64);
        g[k] += __shfl_xor(g[k], 32, 64);
    }
    return (c == 0) ? g[0] : (c == 1) ? g[1] : (c == 2) ? g[2] : g[3];
}

__global__ __launch_bounds__(256) void k2a_scan(
    const float* __restrict__ u_t, const float* __restrict__ dT_t,
    const float* __restrict__ dL_t, const float* __restrict__ Bm_t,
    const float* __restrict__ Cm_t, const float* __restrict__ ATl,
    const float* __restrict__ ALl,
    float* __restrict__ ys_t, float* __restrict__ pscr)
{
    const int be = blockIdx.x;           // b*256 + e
    const int b = be >> 8, e = be & 255;
    const int t = threadIdx.x;
    const int w = __builtin_amdgcn_readfirstlane(t >> 6);
    const int lane = t & 63;
    const int c = lane >> 4, jj = lane & 15;
    const int n = w * 4 + c;

    const float LOG2E = 1.44269504088896340736f;
    const float AT2 = -__expf(ATl[e * NN + n]) * LOG2E;
    const float AL2 = -__expf(ALl[e * NN + n]) * LOG2E;

    const float* dTp = dT_t + ((size_t)be << 12) + 4 * jj;
    const float* dLp = dL_t + ((size_t)be << 12) + 4 * jj;
    const float* up  = u_t  + ((size_t)be << 12) + 4 * jj;
    const float* bmp = Bm_t + ((size_t)(b * NN + n) << 12) + 4 * jj;
    const float* cmp = Cm_t + ((size_t)(b * NN + n) << 12) + 4 * jj;

    float* pg = (w == 0)
        ? (ys_t + ((size_t)be << 12))
        : (pscr + ((size_t)((w - 1) * (BB * EE) + be) << 12));

    float h[4] = {0.f, 0.f, 0.f, 0.f};

    RowRegs rA = row_load(dTp, dLp, up, bmp, cmp, 0);
    RowRegs rB = row_load(dTp, dLp, up, bmp, cmp, 1);

    for (int i = 0; i < HH; i += 2) {
        const int i2 = (i + 2 < HH) ? i + 2 : HH - 1;
        const int i3 = (i + 3 < HH) ? i + 3 : HH - 1;
        RowRegs rC = row_load(dTp, dLp, up, bmp, cmp, i2);
        RowRegs rD = row_load(dTp, dLp, up, bmp, cmp, i3);

        const float g0 = row_scan(rA, AT2, AL2, h, c, jj);
        pg[(i << 6) + 4 * jj + c] = g0;
        const float g1 = row_scan(rB, AT2, AL2, h, c, jj);
        pg[((i + 1) << 6) + 4 * jj + c] = g1;

        rA = rC; rB = rD;
    }
}

// ---------------------------------------------------------------------------
// K2b: ys = gelu(p0+p1+p2+p3 + u*D). 2048 blocks x 256 thr, float4/thread.
// ---------------------------------------------------------------------------
__global__ __launch_bounds__(256) void k2b_fin(
    const float* __restrict__ u_t, const float* __restrict__ pscr,
    const float* __restrict__ Dp, float* __restrict__ ys_t)
{
    const int blk = blockIdx.x;
    const int be = blk >> 2, q = blk & 3;
    const int e = be & 255;
    const float De = Dp[e];
    const size_t base = ((size_t)be << 12) + (q << 10) + (threadIdx.x << 2);
    const size_t plane = ((size_t)(BB * EE)) << 12;

    float4 s        = *(const float4*)(ys_t + base);
    const float4 a1 = *(const float4*)(pscr + base);
    const float4 a2 = *(const float4*)(pscr + plane + base);
    const float4 a3 = *(const float4*)(pscr + 2 * plane + base);
    const float4 uu = *(const float4*)(u_t + base);

    s.x = gelu_exact(fmaf(uu.x, De, ((s.x + a1.x) + (a2.x + a3.x))));
    s.y = gelu_exact(fmaf(uu.y, De, ((s.y + a1.y) + (a2.y + a3.y))));
    s.z = gelu_exact(fmaf(uu.z, De, ((s.z + a1.z) + (a2.z + a3.z))));
    s.w = gelu_exact(fmaf(uu.w, De, ((s.w + a1.w) + (a2.w + a3.w))));

    *(float4*)(ys_t + base) = s;
}

// ---------------------------------------------------------------------------
// K3: out projection. grid = 128 rows x 4 d-chunks. w scalar -> ow s_loads.
// ---------------------------------------------------------------------------
__global__ __launch_bounds__(256) void k3_outproj(
    const float* __restrict__ ys_t,
    const float* __restrict__ ow, const float* __restrict__ ob,
    float* __restrict__ out)
{
    __shared__ float ysL[64][65];

    const int blk = blockIdx.x;
    const int row = blk >> 2;
    const int dc  = blk & 3;
    const int b = row >> 6, i = row & 63;
    const int t = threadIdx.x;
    const int w = __builtin_amdgcn_readfirstlane(t >> 6);
    const int j = t & 63;
    const int d0 = dc * 32 + w * 8;

    float acc[8];
    #pragma unroll
    for (int dd = 0; dd < 8; ++dd) acc[dd] = 0.f;

    for (int ch = 0; ch < 4; ++ch) {
        __syncthreads();
        for (int idx = t; idx < 64 * 64; idx += 256) {
            const int ee = idx >> 6, jj = idx & 63;
            ysL[ee][jj] = ys_t[(((size_t)(b * EE + ch * 64 + ee) * HH + i) << 6) + jj];
        }
        __syncthreads();
        for (int e64 = 0; e64 < 64; ++e64) {
            const float yv = ysL[e64][j];
            const int e = ch * 64 + e64;
            #pragma unroll
            for (int dd = 0; dd < 8; ++dd)
                acc[dd] = fmaf(ow[(d0 + dd) * EE + e], yv, acc[dd]);
        }
    }

    float* orow = out + (size_t)row * (WW * DM) + (size_t)j * DM + d0;
    #pragma unroll
    for (int dd = 0; dd < 8; ++dd) orow[dd] = acc[dd] + ob[d0 + dd];
}

extern "C" void kernel_launch(void* const* d_in, const int* in_sizes, int n_in,
                              void* d_out, int out_size, void* d_ws, size_t ws_size,
                              hipStream_t stream) {
    const float* x    = (const float*)d_in[0];
    const float* ipw  = (const float*)d_in[1];
    const float* ipb  = (const float*)d_in[2];
    const float* xpw  = (const float*)d_in[3];
    const float* xpb  = (const float*)d_in[4];
    const float* dtTw = (const float*)d_in[5];
    const float* dtTb = (const float*)d_in[6];
    const float* dtLw = (const float*)d_in[7];
    const float* dtLb = (const float*)d_in[8];
    const float* ATl  = (const float*)d_in[9];
    const float* ALl  = (const float*)d_in[10];
    const float* Dp   = (const float*)d_in[11];
    const float* ow   = (const float*)d_in[12];
    const float* ob   = (const float*)d_in[13];
    float* out = (float*)d_out;

    float* ws    = (float*)d_ws;
    float* u_t   = ws;
    float* dT_t  = u_t  + (size_t)BB * EE * HW;
    float* dL_t  = dT_t + (size_t)BB * EE * HW;
    float* ys_t  = dL_t + (size_t)BB * EE * HW;
    float* Bm_t  = ys_t + (size_t)BB * EE * HW;
    float* Cm_t  = Bm_t + (size_t)BB * NN * HW;
    float* dbc_g = Cm_t + (size_t)BB * NN * HW;   // [128][16][64]
    float* pscr  = dbc_g + (size_t)BB * HH * NN * WW; // 3 planes of [B,E,H,W]

    k1a_u<<<BB * HH * 8, 256, 0, stream>>>(x, ipw, ipb, u_t);
    k1b1_dbc<<<BB * HH * 8, 256, 0, stream>>>(u_t, xpw, xpb, dbc_g, Bm_t, Cm_t);
    k1b2_delta<<<BB * HH * 4, 256, 0, stream>>>(dbc_g, dtTw, dtTb, dtLw, dtLb,
                                                dT_t, dL_t);
    k2a_scan<<<BB * EE, 256, 0, stream>>>(u_t, dT_t, dL_t, Bm_t, Cm_t,
                                          ATl, ALl, ys_t, pscr);
    k2b_fin<<<BB * EE * 4, 256, 0, stream>>>(u_t, pscr, Dp, ys_t);
    k3_outproj<<<BB * HH * 4, 256, 0, stream>>>(ys_t, ow, ob, out);
}

// Round 10
// 127.734 us; speedup vs baseline: 1.8557x; 1.0557x over previous
//
#include <hip/hip_runtime.h>
#include <math.h>

// Problem constants
#define BB 2
#define HH 64
#define WW 64
#define DM 128
#define EE 256
#define NN 16
#define RR 8
#define HW (HH*WW)          // 4096

__device__ __forceinline__ float gelu_exact(float v) {
    return 0.5f * v * (1.f + erff(v * 0.70710678118654752440f));
}
__device__ __forceinline__ float softplus_f(float v) {
    return fmaxf(v, 0.f) + log1pf(__expf(-fabsf(v)));
}

// DPP row_shr within 16-lane rows: lane L gets lane L-S (same row).
// old = 0 so invalid lanes (jj < S) read 0 under either bound_ctrl
// convention (0 is the additive identity for the B-chain; the A-chain
// masks explicitly with a cndmask). Pure VALU, no LDS pipe.
template<int S>
__device__ __forceinline__ float dpp_shr0(float x) {
    return __int_as_float(__builtin_amdgcn_update_dpp(
        0, __float_as_int(x), 0x110 | S, 0xF, 0xF, false));
}

// ---------------------------------------------------------------------------
// K1a: u = gelu(x@ipw^T + ipb) -> u_t[B,E,H,W]. grid = 128 rows x 8 e-chunks.
// ---------------------------------------------------------------------------
__global__ __launch_bounds__(256) void k1a_u(
    const float* __restrict__ x,
    const float* __restrict__ ipw, const float* __restrict__ ipb,
    float* __restrict__ u_t)
{
    __shared__ float xs[64][129];

    const int blk = blockIdx.x;
    const int row = blk >> 3;            // b*64 + i
    const int ec  = blk & 7;
    const int b = row >> 6, i = row & 63;
    const int t = threadIdx.x;
    const int w = __builtin_amdgcn_readfirstlane(t >> 6);
    const int j = t & 63;

    const float* xrow = x + (size_t)row * (WW * DM);
    for (int idx = t; idx < WW * DM; idx += 256)
        xs[idx >> 7][idx & 127] = xrow[idx];
    __syncthreads();

    const int e0 = ec * 32 + w * 8;
    float acc[8];
    #pragma unroll
    for (int ee = 0; ee < 8; ++ee) acc[ee] = 0.f;

    for (int k = 0; k < DM; ++k) {
        const float xv = xs[j][k];
        #pragma unroll
        for (int ee = 0; ee < 8; ++ee)
            acc[ee] = fmaf(xv, ipw[(e0 + ee) * DM + k], acc[ee]);
    }
    #pragma unroll
    for (int ee = 0; ee < 8; ++ee) {
        const int e = e0 + ee;
        u_t[(((size_t)(b * EE + e) * HH + i) << 6) + j] = gelu_exact(acc[ee] + ipb[e]);
    }
}

// ---------------------------------------------------------------------------
// K1b1: dbc = u@xpw^T (+bias). 1024 blocks, 4 waves, K-split + LDS reduce.
// ---------------------------------------------------------------------------
__global__ __launch_bounds__(256) void k1b1_dbc(
    const float* __restrict__ u_t,
    const float* __restrict__ xpw, const float* __restrict__ xpb,
    float* __restrict__ dbc_g, float* __restrict__ Bm_t, float* __restrict__ Cm_t)
{
    __shared__ float xw[6][260];
    __shared__ float part[4][6][68];

    const int blk = blockIdx.x;
    const int cg = blk & 7;
    const int row = blk >> 3;            // b*64 + i
    const int b = row >> 6, i = row & 63;
    const int c0 = 6 * cg;
    const int t = threadIdx.x;
    const int w2 = __builtin_amdgcn_readfirstlane(t >> 6);
    const int j = t & 63;

    for (int idx = t; idx < 6 * 64; idx += 256) {
        const int cc = idx >> 6, e4 = idx & 63;
        *(float4*)&xw[cc][4 * e4] = ((const float4*)xpw)[(size_t)(c0 + cc) * 64 + e4];
    }
    __syncthreads();

    const float* ub = u_t + (((size_t)(b * EE)) << 12) + (i << 6) + j;
    const int ebase = 64 * w2;

    float acc[6] = {0.f, 0.f, 0.f, 0.f, 0.f, 0.f};
    for (int e4 = 0; e4 < 16; ++e4) {
        const int e = ebase + 4 * e4;
        const float u0 = ub[(size_t)(e + 0) << 12];
        const float u1 = ub[(size_t)(e + 1) << 12];
        const float u2 = ub[(size_t)(e + 2) << 12];
        const float u3 = ub[(size_t)(e + 3) << 12];
        #pragma unroll
        for (int cc = 0; cc < 6; ++cc) {
            const float4 wv = *(const float4*)&xw[cc][e];
            acc[cc] = fmaf(u0, wv.x, acc[cc]);
            acc[cc] = fmaf(u1, wv.y, acc[cc]);
            acc[cc] = fmaf(u2, wv.z, acc[cc]);
            acc[cc] = fmaf(u3, wv.w, acc[cc]);
        }
    }
    #pragma unroll
    for (int cc = 0; cc < 6; ++cc) part[w2][cc][j] = acc[cc];
    __syncthreads();

    for (int idx = t; idx < 6 * 64; idx += 256) {
        const int cc = idx >> 6, j2 = idx & 63;
        const int c = c0 + cc;
        const float s = ((part[0][cc][j2] + part[1][cc][j2]) +
                         (part[2][cc][j2] + part[3][cc][j2])) + xpb[c];
        if (c < 16) {
            dbc_g[((size_t)row * 16 + c) * 64 + j2] = s;
        } else if (c < 32) {
            const int n = c - 16;
            Bm_t[(((size_t)(b * NN + n) * HH + i) << 6) + j2] = s;
        } else {
            const int n = c - 32;
            Cm_t[(((size_t)(b * NN + n) * HH + i) << 6) + j2] = s;
        }
    }
}

// ---------------------------------------------------------------------------
// K1b2: deltaT/L = softplus(d@dtw^T + b). 512 blocks. e scalar -> s_loads.
// ---------------------------------------------------------------------------
__global__ __launch_bounds__(256) void k1b2_delta(
    const float* __restrict__ dbc_g,
    const float* __restrict__ dtTw, const float* __restrict__ dtTb,
    const float* __restrict__ dtLw, const float* __restrict__ dtLb,
    float* __restrict__ dT_t, float* __restrict__ dL_t)
{
    __shared__ float db[16][68];

    const int blk = blockIdx.x;
    const int eq = blk & 3;
    const int row = blk >> 2;            // b*64 + i
    const int b = row >> 6, i = row & 63;
    const int t = threadIdx.x;
    const int w2 = __builtin_amdgcn_readfirstlane(t >> 6);
    const int j = t & 63;

    for (int idx = t; idx < 16 * 64; idx += 256) {
        const int c = idx >> 6, j2 = idx & 63;
        db[c][j2] = dbc_g[((size_t)row * 16 + c) * 64 + j2];
    }
    __syncthreads();

    float dtv[8], dlv[8];
    #pragma unroll
    for (int r = 0; r < 8; ++r) { dtv[r] = db[r][j]; dlv[r] = db[8 + r][j]; }

    #pragma unroll 4
    for (int k = 0; k < 16; ++k) {
        const int e = 64 * eq + w2 + 4 * k;
        float sT = dtTb[e], sL = dtLb[e];
        #pragma unroll
        for (int r = 0; r < 8; ++r) {
            sT = fmaf(dtv[r], dtTw[e * RR + r], sT);
            sL = fmaf(dlv[r], dtLw[e * RR + r], sL);
        }
        dT_t[(((size_t)(b * EE + e) * HH + i) << 6) + j] = softplus_f(sT);
        dL_t[(((size_t)(b * EE + e) * HH + i) << 6) + j] = softplus_f(sL);
    }
}

// ---------------------------------------------------------------------------
// K2a: wavefront scan + fused finalize. Block per (b,e): 4 waves,
// __launch_bounds__(256,2) so the distance-2 prefetch stays in registers
// (R8's VGPR=48 showed the compiler demoted it). Row loop: DPP scan, then
// per-wave 4-channel reduce (shfl_xor, terminal) -> LDS parts[w][i][col]
// (col stride-1 writes, conflict-free, NO per-row barrier). One syncthreads
// after the loop, then distributed finalize: sum 4 partials + u*D + gelu,
// coalesced stores (replaces the old k2b kernel).
// ---------------------------------------------------------------------------
struct RowRegs { float4 dT, dL, u, bm, cm; };

__device__ __forceinline__ RowRegs row_load(
    const float* dTp, const float* dLp, const float* up,
    const float* bmp, const float* cmp, int i)
{
    RowRegs r;
    const int off = i << 6;
    r.dT = *(const float4*)(dTp + off);
    r.dL = *(const float4*)(dLp + off);
    r.u  = *(const float4*)(up  + off);
    r.bm = *(const float4*)(bmp + off);
    r.cm = *(const float4*)(cmp + off);
    return r;
}

__device__ __forceinline__ float row_scan(
    const RowRegs& r, float AT2, float AL2, float* h, int c, int jj)
{
    const float dTv[4] = {r.dT.x, r.dT.y, r.dT.z, r.dT.w};
    const float dLv[4] = {r.dL.x, r.dL.y, r.dL.z, r.dL.w};
    const float uv[4]  = {r.u.x,  r.u.y,  r.u.z,  r.u.w};
    const float bmv[4] = {r.bm.x, r.bm.y, r.bm.z, r.bm.w};
    const float cmv[4] = {r.cm.x, r.cm.y, r.cm.z, r.cm.w};

    // local inclusive scan over this lane's 4 cols
    float cumA[4], cumB[4];
    {
        const float aT = exp2f(dTv[0] * AT2);
        cumA[0] = exp2f(dLv[0] * AL2);
        cumB[0] = fmaf(aT, h[0], (dTv[0] + dLv[0]) * bmv[0] * uv[0]);
    }
    #pragma unroll
    for (int k = 1; k < 4; ++k) {
        const float aT = exp2f(dTv[k] * AT2);
        const float aL = exp2f(dLv[k] * AL2);
        const float bk = fmaf(aT, h[k], (dTv[k] + dLv[k]) * bmv[k] * uv[k]);
        cumB[k] = fmaf(aL, cumB[k - 1], bk);
        cumA[k] = aL * cumA[k - 1];
    }

    // 16-lane segmented Hillis-Steele on aggregates — all DPP (VALU).
    float Ag = cumA[3], Bg = cumB[3];
    { const float uA = dpp_shr0<1>(Ag), uB = dpp_shr0<1>(Bg);
      Bg = fmaf(Ag, uB, Bg); Ag *= (jj >= 1) ? uA : 1.f; }
    { const float uA = dpp_shr0<2>(Ag), uB = dpp_shr0<2>(Bg);
      Bg = fmaf(Ag, uB, Bg); Ag *= (jj >= 2) ? uA : 1.f; }
    { const float uA = dpp_shr0<4>(Ag), uB = dpp_shr0<4>(Bg);
      Bg = fmaf(Ag, uB, Bg); Ag *= (jj >= 4) ? uA : 1.f; }
    { const float uB = dpp_shr0<8>(Bg);
      Bg = fmaf(Ag, uB, Bg); }              // Ag not needed afterward
    const float pB = dpp_shr0<1>(Bg);        // exclusive prefix; jj==0 -> 0

    float g[4];
    #pragma unroll
    for (int k = 0; k < 4; ++k) {
        h[k] = fmaf(cumA[k], pB, cumB[k]);
        g[k] = h[k] * cmv[k];
    }
    // terminal cross-channel reduce over c = lane>>4 (off critical path)
    #pragma unroll
    for (int k = 0; k < 4; ++k) {
        g[k] += __shfl_xor(g[k], 16, 64);
        g[k] += __shfl_xor(g[k], 32, 64);
    }
    return (c == 0) ? g[0] : (c == 1) ? g[1] : (c == 2) ? g[2] : g[3];
}

__global__ __launch_bounds__(256, 2) void k2a_scan(
    const float* __restrict__ u_t, const float* __restrict__ dT_t,
    const float* __restrict__ dL_t, const float* __restrict__ Bm_t,
    const float* __restrict__ Cm_t, const float* __restrict__ ATl,
    const float* __restrict__ ALl, const float* __restrict__ Dp,
    float* __restrict__ ys_t)
{
    __shared__ float parts[4][64][64];   // 64KB exactly

    const int be = blockIdx.x;           // b*256 + e
    const int b = be >> 8, e = be & 255;
    const int t = threadIdx.x;
    const int w = __builtin_amdgcn_readfirstlane(t >> 6);
    const int lane = t & 63;
    const int c = lane >> 4, jj = lane & 15;
    const int n = w * 4 + c;
    const int col = 4 * jj + c;

    const float LOG2E = 1.44269504088896340736f;
    const float AT2 = -__expf(ATl[e * NN + n]) * LOG2E;
    const float AL2 = -__expf(ALl[e * NN + n]) * LOG2E;

    const float* dTp = dT_t + ((size_t)be << 12) + 4 * jj;
    const float* dLp = dL_t + ((size_t)be << 12) + 4 * jj;
    const float* up  = u_t  + ((size_t)be << 12) + 4 * jj;
    const float* bmp = Bm_t + ((size_t)(b * NN + n) << 12) + 4 * jj;
    const float* cmp = Cm_t + ((size_t)(b * NN + n) << 12) + 4 * jj;

    float h[4] = {0.f, 0.f, 0.f, 0.f};

    RowRegs rA = row_load(dTp, dLp, up, bmp, cmp, 0);
    RowRegs rB = row_load(dTp, dLp, up, bmp, cmp, 1);

    for (int i = 0; i < HH; i += 2) {
        const int i2 = (i + 2 < HH) ? i + 2 : HH - 1;
        const int i3 = (i + 3 < HH) ? i + 3 : HH - 1;
        RowRegs rC = row_load(dTp, dLp, up, bmp, cmp, i2);
        RowRegs rD = row_load(dTp, dLp, up, bmp, cmp, i3);

        const float g0 = row_scan(rA, AT2, AL2, h, c, jj);
        parts[w][i][col] = g0;
        const float g1 = row_scan(rB, AT2, AL2, h, c, jj);
        parts[w][i + 1][col] = g1;

        rA = rC; rB = rD;
    }

    __syncthreads();

    // distributed finalize (was kernel k2b): thread (t>>6, t&63) sums the
    // 4 wave-partials for 16 rows at its column; coalesced u loads/stores.
    const float De = Dp[e];
    const int fcol = t & 63;
    const int r0 = (t >> 6) * 16;
    const float* uf = u_t + ((size_t)be << 12) + fcol;
    float* ysf = ys_t + ((size_t)be << 12) + fcol;
    #pragma unroll 4
    for (int q = 0; q < 16; ++q) {
        const int i = r0 + q;
        const float s = ((parts[0][i][fcol] + parts[1][i][fcol]) +
                         (parts[2][i][fcol] + parts[3][i][fcol]));
        ysf[i << 6] = gelu_exact(fmaf(uf[i << 6], De, s));
    }
}

// ---------------------------------------------------------------------------
// K3: out projection. grid = 128 rows x 4 d-chunks. w scalar -> ow s_loads.
// ---------------------------------------------------------------------------
__global__ __launch_bounds__(256) void k3_outproj(
    const float* __restrict__ ys_t,
    const float* __restrict__ ow, const float* __restrict__ ob,
    float* __restrict__ out)
{
    __shared__ float ysL[64][65];

    const int blk = blockIdx.x;
    const int row = blk >> 2;
    const int dc  = blk & 3;
    const int b = row >> 6, i = row & 63;
    const int t = threadIdx.x;
    const int w = __builtin_amdgcn_readfirstlane(t >> 6);
    const int j = t & 63;
    const int d0 = dc * 32 + w * 8;

    float acc[8];
    #pragma unroll
    for (int dd = 0; dd < 8; ++dd) acc[dd] = 0.f;

    for (int ch = 0; ch < 4; ++ch) {
        __syncthreads();
        for (int idx = t; idx < 64 * 64; idx += 256) {
            const int ee = idx >> 6, jj = idx & 63;
            ysL[ee][jj] = ys_t[(((size_t)(b * EE + ch * 64 + ee) * HH + i) << 6) + jj];
        }
        __syncthreads();
        for (int e64 = 0; e64 < 64; ++e64) {
            const float yv = ysL[e64][j];
            const int e = ch * 64 + e64;
            #pragma unroll
            for (int dd = 0; dd < 8; ++dd)
                acc[dd] = fmaf(ow[(d0 + dd) * EE + e], yv, acc[dd]);
        }
    }

    float* orow = out + (size_t)row * (WW * DM) + (size_t)j * DM + d0;
    #pragma unroll
    for (int dd = 0; dd < 8; ++dd) orow[dd] = acc[dd] + ob[d0 + dd];
}

extern "C" void kernel_launch(void* const* d_in, const int* in_sizes, int n_in,
                              void* d_out, int out_size, void* d_ws, size_t ws_size,
                              hipStream_t stream) {
    const float* x    = (const float*)d_in[0];
    const float* ipw  = (const float*)d_in[1];
    const float* ipb  = (const float*)d_in[2];
    const float* xpw  = (const float*)d_in[3];
    const float* xpb  = (const float*)d_in[4];
    const float* dtTw = (const float*)d_in[5];
    const float* dtTb = (const float*)d_in[6];
    const float* dtLw = (const float*)d_in[7];
    const float* dtLb = (const float*)d_in[8];
    const float* ATl  = (const float*)d_in[9];
    const float* ALl  = (const float*)d_in[10];
    const float* Dp   = (const float*)d_in[11];
    const float* ow   = (const float*)d_in[12];
    const float* ob   = (const float*)d_in[13];
    float* out = (float*)d_out;

    float* ws    = (float*)d_ws;
    float* u_t   = ws;
    float* dT_t  = u_t  + (size_t)BB * EE * HW;
    float* dL_t  = dT_t + (size_t)BB * EE * HW;
    float* ys_t  = dL_t + (size_t)BB * EE * HW;
    float* Bm_t  = ys_t + (size_t)BB * EE * HW;
    float* Cm_t  = Bm_t + (size_t)BB * NN * HW;
    float* dbc_g = Cm_t + (size_t)BB * NN * HW;   // [128][16][64]

    k1a_u<<<BB * HH * 8, 256, 0, stream>>>(x, ipw, ipb, u_t);
    k1b1_dbc<<<BB * HH * 8, 256, 0, stream>>>(u_t, xpw, xpb, dbc_g, Bm_t, Cm_t);
    k1b2_delta<<<BB * HH * 4, 256, 0, stream>>>(dbc_g, dtTw, dtTb, dtLw, dtLb,
                                                dT_t, dL_t);
    k2a_scan<<<BB * EE, 256, 0, stream>>>(u_t, dT_t, dL_t, Bm_t, Cm_t,
                                          ATl, ALl, Dp, ys_t);
    k3_outproj<<<BB * HH * 4, 256, 0, stream>>>(ys_t, ow, ob, out);
}